// Round 10
// baseline (537.467 us; speedup 1.0000x reference)
//
#include <hip/hip_runtime.h>
#include <hip/hip_bf16.h>
#include <math.h>

// ============================================================================
// Fractal-flame chaos game — bit-exact JAX RNG reproduction.
// R6: R4 sort pipeline + WAVE-LEVEL SEGMENTED COMBINE in accum_k.
// R5 evidence: 1-entry register cache changed nothing => hot chunks are
// interleaved clusters of hot pixels (run length ~1), and same-address LDS
// atomic serialization (~64-way x ~tens of cycles) dominates. Butterfly
// shfl_xor absorb over (cell,mask,16-float payload) leaves one leader per
// distinct key per wave => no intra-wave same-address atomics at all.
// ============================================================================

#define RNG_PARTITIONABLE 1
#define COLSUM_F32_ACCUM 1

typedef unsigned int u32;
typedef unsigned short u16;

static constexpr int FN = 8;
static constexpr int HH = 1024;
static constexpr int WW = 1024;
static constexpr int NP = 65536;
static constexpr int TI = 48;
static constexpr int WARM = 8;
static constexpr int HWPIX = HH * WW;
static constexpr int NSPLAT = TI - WARM;        // 40
static constexpr int NREC = NSPLAT * NP;        // 2,621,440
static constexpr int NBKT = 512;                // 2-row full-width bands
static constexpr int NBLK = NP / 256;           // 256 chaos blocks
static constexpr u32 CHUNK = 8192;              // records per accum wg
static constexpr int MAXWG = 2048;              // bound: 512 + 320
static constexpr int TILE4 = 3 * 1024;          // float4 cells per partial tile

static constexpr int META_CUMPT = 0;    // 64 f32
static constexpr int META_AFF   = 64;   // 48 f32
static constexpr int META_CT    = 112;  // 24 f32
static constexpr int META_BG    = 136;  // 3 f32
static constexpr int META_FLAG  = 139;  // 1 f32
static constexpr int META_KEYS  = 140;  // 96 u32
static constexpr int META_KX    = 236;  // 2 u32
static constexpr int META_K2S   = 238;  // 2 u32

struct U2 { u32 x, y; };

// ---------------------------------------------------------------- threefry2x32
__device__ __forceinline__ U2 tf2x32(u32 k0, u32 k1, u32 c0, u32 c1) {
  u32 ks2 = k0 ^ k1 ^ 0x1BD11BDAu;
  u32 x0 = c0 + k0, x1 = c1 + k1;
#define TF_R(r) { x0 += x1; x1 = (x1 << (r)) | (x1 >> (32 - (r))); x1 ^= x0; }
  TF_R(13) TF_R(15) TF_R(26) TF_R(6)
  x0 += k1; x1 += ks2 + 1u;
  TF_R(17) TF_R(29) TF_R(16) TF_R(24)
  x0 += ks2; x1 += k0 + 2u;
  TF_R(13) TF_R(15) TF_R(26) TF_R(6)
  x0 += k0; x1 += k1 + 3u;
  TF_R(17) TF_R(29) TF_R(16) TF_R(24)
  x0 += k1; x1 += ks2 + 4u;
  TF_R(13) TF_R(15) TF_R(26) TF_R(6)
  x0 += ks2; x1 += k0 + 5u;
#undef TF_R
  return {x0, x1};
}

__device__ __forceinline__ u32 rbits(U2 key, u32 i, u32 halfN) {
#if RNG_PARTITIONABLE
  (void)halfN;
  U2 r = tf2x32(key.x, key.y, 0u, i);
  return r.x ^ r.y;
#else
  if (i < halfN) { U2 r = tf2x32(key.x, key.y, i, i + halfN); return r.x; }
  else           { U2 r = tf2x32(key.x, key.y, i - halfN, i); return r.y; }
#endif
}

__device__ __forceinline__ float unitf(u32 b) {  // jax uniform [0,1)
  return __uint_as_float((b >> 9) | 0x3F800000u) - 1.0f;
}

// ---------------------------------------------------------------- bf16 helpers
__device__ __forceinline__ float bf2f(u16 h) { return __uint_as_float(((u32)h) << 16); }
__device__ __forceinline__ float rndbf(float x) {
  u32 u = __float_as_uint(x);
  u32 r = (u + 0x7FFFu + ((u >> 16) & 1u)) & 0xFFFF0000u;
  return __uint_as_float(r);
}
__device__ __forceinline__ float rnd_m(float x, bool bf) { return bf ? rndbf(x) : x; }
__device__ __forceinline__ float ldf(const void* p, int i, bool bf) {
  return bf ? bf2f(((const u16*)p)[i]) : ((const float*)p)[i];
}
__device__ __forceinline__ float exp_cr(float x) { return (float)exp((double)x); }
__device__ __forceinline__ float sigchain(float x, bool bf) {
  float e = rnd_m(exp_cr(-x), bf);
  float d = rnd_m(1.0f + e, bf);
  return rnd_m(1.0f / d, bf);
}

// ============================================================== setup kernel
__global__ __launch_bounds__(64) void setup_kernel(const void* pn, const void* affp,
                                                   const void* ctp, const void* bgp,
                                                   float* meta) {
  __shared__ int vote;
  __shared__ float sP[64];
  __shared__ u32 sroot[8];
  int tid = threadIdx.x;
  if (tid == 0) vote = 0;
  __syncthreads();
  {
    float v = fabsf(bf2f(((const u16*)pn)[tid]));
    if (v > 1e-4f && v < 16.0f) atomicAdd(&vote, 1);
  }
  __syncthreads();
  bool bf = (vote >= 50);

  if (tid == 0) {
    meta[META_FLAG] = bf ? 1.0f : 0.0f;
    u32* mu = (u32*)meta;
#if RNG_PARTITIONABLE
    U2 kx = tf2x32(0u, 42u, 0u, 0u);
    U2 ks = tf2x32(0u, 42u, 0u, 1u);
    U2 kl = tf2x32(0u, 42u, 0u, 2u);
    U2 k2 = tf2x32(ks.x, ks.y, 0u, 1u);
#else
    U2 t0 = tf2x32(0u, 42u, 0u, 3u), t1 = tf2x32(0u, 42u, 1u, 4u), t2 = tf2x32(0u, 42u, 2u, 5u);
    U2 kx{t0.x, t1.x}, ks{t2.x, t0.y}, kl{t1.y, t2.y};
    U2 r0 = tf2x32(ks.x, ks.y, 0u, 2u), r1 = tf2x32(ks.x, ks.y, 1u, 3u);
    U2 k2{r0.y, r1.y};
#endif
    sroot[0] = kx.x; sroot[1] = kx.y; sroot[2] = ks.x; sroot[3] = ks.y;
    sroot[4] = kl.x; sroot[5] = kl.y; sroot[6] = k2.x; sroot[7] = k2.y;
    mu[META_KX] = kx.x; mu[META_KX + 1] = kx.y;
    mu[META_K2S] = k2.x; mu[META_K2S + 1] = k2.y;
  }

  float c001 = bf ? 0.00099945068359375f : 0.001f;
  sP[tid] = rnd_m(sigchain(ldf(pn, tid, bf), bf) + c001, bf);
  if (tid < 48) meta[META_AFF + tid] = ldf(affp, tid, bf);
  if (tid < 24) meta[META_CT + tid] = sigchain(ldf(ctp, tid, bf), bf);
  if (tid < 3)  meta[META_BG + tid] = sigchain(ldf(bgp, tid, bf), bf);
  __syncthreads();

  if (tid < 48) {
    U2 kl{sroot[4], sroot[5]};
    u32* mu = (u32*)meta;
#if RNG_PARTITIONABLE
    U2 kt = tf2x32(kl.x, kl.y, 0u, (u32)tid);
#else
    u32 e0 = 2u * tid, e1 = 2u * tid + 1u;
    u32 w0 = (e0 < 48u) ? tf2x32(kl.x, kl.y, e0, e0 + 48u).x : tf2x32(kl.x, kl.y, e0 - 48u, e0).y;
    u32 w1 = (e1 < 48u) ? tf2x32(kl.x, kl.y, e1, e1 + 48u).x : tf2x32(kl.x, kl.y, e1 - 48u, e1).y;
    U2 kt{w0, w1};
#endif
    mu[META_KEYS + 2 * tid]     = kt.x;
    mu[META_KEYS + 2 * tid + 1] = kt.y;
  }

  if (tid < 8) {
    int c = tid;
    float a[8];
#if COLSUM_F32_ACCUM
    float cs = 0.0f;
    for (int r = 0; r < 8; ++r) cs += sP[r * 8 + c];
    cs = rnd_m(cs, bf);
#else
    float cs = 0.0f;
    for (int r = 0; r < 8; ++r) cs = rnd_m(cs + sP[r * 8 + c], bf);
#endif
    for (int r = 0; r < 8; ++r) a[r] = rnd_m(sP[r * 8 + c] / cs, bf);
    float b0 = rnd_m(a[0] + a[1], bf), b1 = rnd_m(a[2] + a[3], bf);
    float b2 = rnd_m(a[4] + a[5], bf), b3 = rnd_m(a[6] + a[7], bf);
    float c0 = rnd_m(b0 + b1, bf), c1v = rnd_m(b2 + b3, bf);
    float d0 = rnd_m(c0 + c1v, bf);
    float s5 = rnd_m(c0 + b2, bf);
    float cum[8] = { a[0], b0, rnd_m(b0 + a[2], bf), c0,
                     rnd_m(c0 + a[4], bf), s5, rnd_m(s5 + a[6], bf), d0 };
    for (int r = 0; r < 8; ++r) meta[META_CUMPT + c * 8 + r] = cum[r];
  }
}

// ====================================================== chaos + record kernel
// 8B record: w0 = fxq<<16 | fyq (16-bit frac quantization);
//            w1 = s<<22 | (yi+1)<<11 | (xi+1);  w1==~0 => invalid (off-screen)
__global__ __launch_bounds__(256) void chaos_record(const float* __restrict__ meta,
                                                    uint2* __restrict__ recU,
                                                    u32* __restrict__ counts) {
  __shared__ float cumPT[64];
  __shared__ float aff8[64];
  __shared__ u32 keyw[96];
  __shared__ u32 rk[4];
  __shared__ u32 cnt[NBKT];
  int tid = threadIdx.x;
  if (tid < 64) cumPT[tid] = meta[META_CUMPT + tid];
  if (tid < 48) aff8[(tid / 6) * 8 + (tid % 6)] = meta[META_AFF + tid];
  const u32* mu = (const u32*)meta;
  if (tid < 96) keyw[tid] = mu[META_KEYS + tid];
  if (tid < 4)  rk[tid] = mu[META_KX + tid];
  for (int b = tid; b < NBKT; b += 256) cnt[b] = 0u;
  __syncthreads();

  u32 n = blockIdx.x * 256u + (u32)tid;
  U2 kx{rk[0], rk[1]}, k2{rk[2], rk[3]};
  float x = fmaxf(-1.0f, unitf(rbits(kx, 2u * n,      65536u)) * 2.0f - 1.0f);
  float y = fmaxf(-1.0f, unitf(rbits(kx, 2u * n + 1u, 65536u)) * 2.0f - 1.0f);
  int s = (int)(rbits(k2, n, 32768u) & 7u);

  float uv[8];
  // warmup batch (no records)
#pragma unroll
  for (int j = 0; j < 8; ++j) {
    U2 kt{keyw[2 * j], keyw[2 * j + 1]};
    uv[j] = unitf(rbits(kt, n, 32768u));
  }
#pragma unroll
  for (int j = 0; j < 8; ++j) {
    float u = uv[j];
    float4 c0 = *(const float4*)&cumPT[s * 8];
    float4 c1 = *(const float4*)&cumPT[s * 8 + 4];
    int cntc = (c0.x < u) + (c0.y < u) + (c0.z < u) + (c0.w < u)
             + (c1.x < u) + (c1.y < u) + (c1.z < u) + (c1.w < u);
    int nxt = cntc < 7 ? cntc : 7;
    float4 A0 = *(const float4*)&aff8[nxt * 8];
    float4 A1 = *(const float4*)&aff8[nxt * 8 + 4];
    float xn = A0.x * x + A0.y * y + A0.z;
    float yn = A0.w * x + A1.x * y + A1.y;
    x = xn; y = yn; s = nxt;
  }

  for (int b = 1; b < 6; ++b) {
#pragma unroll
    for (int j = 0; j < 8; ++j) {
      U2 kt{keyw[16 * b + 2 * j], keyw[16 * b + 2 * j + 1]};
      uv[j] = unitf(rbits(kt, n, 32768u));
    }
#pragma unroll
    for (int j = 0; j < 8; ++j) {
      float u = uv[j];
      float4 c0 = *(const float4*)&cumPT[s * 8];
      float4 c1 = *(const float4*)&cumPT[s * 8 + 4];
      int cntc = (c0.x < u) + (c0.y < u) + (c0.z < u) + (c0.w < u)
               + (c1.x < u) + (c1.y < u) + (c1.z < u) + (c1.w < u);
      int nxt = cntc < 7 ? cntc : 7;
      float4 A0 = *(const float4*)&aff8[nxt * 8];
      float4 A1 = *(const float4*)&aff8[nxt * 8 + 4];
      float xn = A0.x * x + A0.y * y + A0.z;
      float yn = A0.w * x + A1.x * y + A1.y;
      x = xn; y = yn; s = nxt;

      float gx = (x + 1.0f) * 0.5f * 1024.0f - 0.5f;
      float gy = (y + 1.0f) * 0.5f * 1024.0f - 0.5f;
      float fx0 = floorf(gx), fy0 = floorf(gy);
      float fx = gx - fx0, fy = gy - fy0;
      int xi = (int)fx0, yi = (int)fy0;
      u32 w0 = 0u, w1 = 0xFFFFFFFFu;
      if (yi >= -1 && yi < 1024 && xi >= -1 && xi < 1024) {
        int yc = yi < 0 ? 0 : yi;
        u32 fxq = (u32)(fx * 65536.0f); if (fxq > 65535u) fxq = 65535u;
        u32 fyq = (u32)(fy * 65536.0f); if (fyq > 65535u) fyq = 65535u;
        w0 = (fxq << 16) | fyq;
        w1 = ((u32)s << 22) | ((u32)(yi + 1) << 11) | (u32)(xi + 1);
        atomicAdd(&cnt[(u32)(yc >> 1)], 1u);
      }
      recU[((b - 1) * 8 + j) * NP + n] = make_uint2(w0, w1);
    }
  }
  __syncthreads();
  for (int bb = tid; bb < NBKT; bb += 256) counts[bb * NBLK + blockIdx.x] = cnt[bb];
}

// ================================================== prefix kernels (counting sort)
__global__ __launch_bounds__(256) void pre_a(u32* __restrict__ counts,
                                             u32* __restrict__ totals) {
  int bkt = blockIdx.x, tid = threadIdx.x;
  __shared__ u32 sc[256];
  u32 v = counts[bkt * NBLK + tid];
  sc[tid] = v;
  __syncthreads();
  for (int off = 1; off < 256; off <<= 1) {
    u32 t = (tid >= off) ? sc[tid - off] : 0u;
    __syncthreads();
    sc[tid] += t;
    __syncthreads();
  }
  counts[bkt * NBLK + tid] = sc[tid] - v;     // exclusive within bucket
  if (tid == 255) totals[bkt] = sc[tid];
}

__global__ __launch_bounds__(512) void pre_b(const u32* __restrict__ totals,
                                             u32* __restrict__ starts) {
  int tid = threadIdx.x;
  __shared__ u32 sc[512];
  u32 v = totals[tid];
  sc[tid] = v;
  __syncthreads();
  for (int off = 1; off < 512; off <<= 1) {
    u32 t = (tid >= off) ? sc[tid - off] : 0u;
    __syncthreads();
    sc[tid] += t;
    __syncthreads();
  }
  starts[tid] = sc[tid] - v;
  if (tid == 511) starts[512] = sc[tid];
}

// =============================================== chunk assignment (equal work)
__global__ __launch_bounds__(512) void assign_k(const u32* __restrict__ starts,
                                                u32* __restrict__ poff,
                                                u32* __restrict__ wgmap) {
  __shared__ u32 sc[512];
  int tid = threadIdx.x;
  u32 len = starts[tid + 1] - starts[tid];
  u32 np = (len + CHUNK - 1) / CHUNK;           // 0 if empty
  sc[tid] = np;
  __syncthreads();
  for (int off = 1; off < 512; off <<= 1) {
    u32 t = (tid >= off) ? sc[tid - off] : 0u;
    __syncthreads();
    sc[tid] += t;
    __syncthreads();
  }
  u32 excl = sc[tid] - np;
  poff[tid] = excl;
  if (tid == 511) poff[512] = sc[511];
  u32 total = sc[511];
  for (u32 j = 0; j < np; ++j) wgmap[excl + j] = ((u32)tid << 16) | j;
  for (u32 i = total + (u32)tid; i < (u32)MAXWG; i += 512u) wgmap[i] = 0xFFFFFFFFu;
}

// ================================= equal-work per-chunk LDS accumulation
// Wave-level butterfly absorb: per record-iteration, lanes with equal
// (cell,mask) combine their 16-float corner payloads via shfl_xor; the
// surviving leader issues conflict-free LDS atomics. Eliminates intra-wave
// same-address serialization for ANY key pattern (R5 evidence: interleaved
// hot pixels defeat run-based caching).
__global__ __launch_bounds__(256) void accum_k(const uint2* __restrict__ recS,
                                               const u32* __restrict__ starts,
                                               const u32* __restrict__ wgmap,
                                               const float* __restrict__ meta,
                                               float4* __restrict__ scratch) {
  u32 a = wgmap[blockIdx.x];
  if (a == 0xFFFFFFFFu) return;
  __shared__ float4 tile4[TILE4];               // 3 rows x 1024 cols, rgbw — 48 KB
  __shared__ float4 ctv[8];
  int tid = threadIdx.x;
  int lane = tid & 63;
  int b = (int)(a >> 16);
  u32 j = a & 0xFFFFu;
  u32 rs = starts[b] + j * CHUNK;
  u32 re = starts[b + 1];
  u32 rlim = rs + CHUNK;
  if (rlim < re) re = rlim;
  u32 iters = (re - rs + 255u) / 256u;

  for (int i = tid; i < TILE4; i += 256) tile4[i] = make_float4(0.f, 0.f, 0.f, 0.f);
  if (tid < 8)
    ctv[tid] = make_float4(meta[META_CT + tid], meta[META_CT + 8 + tid],
                           meta[META_CT + 16 + tid], 1.0f);
  __syncthreads();

  float* tile = (float*)tile4;
  for (u32 it = 0; it < iters; ++it) {
    u32 i = rs + it * 256u + (u32)tid;
    int ikey = 0x7FFFFFFF;
    u32 mask = 0u;
    float s[16];
#pragma unroll
    for (int q = 0; q < 16; ++q) s[q] = 0.0f;
    if (i < re) {
      uint2 r = recS[i];
      int xi = (int)(r.y & 0x7FFu) - 1;
      int yi = (int)((r.y >> 11) & 0x7FFu) - 1;
      u32 sfn = (r.y >> 22) & 7u;
      float fx = (float)(r.x >> 16) * (1.0f / 65536.0f);
      float fy = (float)(r.x & 0xFFFFu) * (1.0f / 65536.0f);
      float ofx = 1.0f - fx, ofy = 1.0f - fy;
      float w00 = ofx * ofy, w10 = fx * ofy, w01 = ofx * fy, w11 = fx * fy;
      float4 cv = ctv[sfn];
      ikey = (yi - 2 * b) * 1024 + xi;
      if ((u32)yi < 1024u) {
        if ((u32)xi < 1024u)       mask |= 1u;
        if ((u32)(xi + 1) < 1024u) mask |= 2u;
      }
      if ((u32)(yi + 1) < 1024u) {
        if ((u32)xi < 1024u)       mask |= 4u;
        if ((u32)(xi + 1) < 1024u) mask |= 8u;
      }
      s[0]  = w00 * cv.x; s[1]  = w00 * cv.y; s[2]  = w00 * cv.z; s[3]  = w00;
      s[4]  = w10 * cv.x; s[5]  = w10 * cv.y; s[6]  = w10 * cv.z; s[7]  = w10;
      s[8]  = w01 * cv.x; s[9]  = w01 * cv.y; s[10] = w01 * cv.z; s[11] = w01;
      s[12] = w11 * cv.x; s[13] = w11 * cv.y; s[14] = w11 * cv.z; s[15] = w11;
    }

    int alive = 1;
#pragma unroll
    for (int d = 1; d < 64; d <<= 1) {
      int pk = __shfl_xor(ikey, d, 64);
      int pm = __shfl_xor((int)mask, d, 64);
      int pa = __shfl_xor(alive, d, 64);
      float ps[16];
#pragma unroll
      for (int q = 0; q < 16; ++q) ps[q] = __shfl_xor(s[q], d, 64);
      bool match = alive && pa && (pk == ikey) && (pm == (int)mask);
      if (match) {
        if (lane & d) {
          alive = 0;
        } else {
#pragma unroll
          for (int q = 0; q < 16; ++q) s[q] += ps[q];
        }
      }
    }

    if (alive && mask) {
      if (mask & 1u) { int q = ikey * 4;
        atomicAdd(&tile[q], s[0]); atomicAdd(&tile[q + 1], s[1]);
        atomicAdd(&tile[q + 2], s[2]); atomicAdd(&tile[q + 3], s[3]); }
      if (mask & 2u) { int q = (ikey + 1) * 4;
        atomicAdd(&tile[q], s[4]); atomicAdd(&tile[q + 1], s[5]);
        atomicAdd(&tile[q + 2], s[6]); atomicAdd(&tile[q + 3], s[7]); }
      if (mask & 4u) { int q = (ikey + 1024) * 4;
        atomicAdd(&tile[q], s[8]); atomicAdd(&tile[q + 1], s[9]);
        atomicAdd(&tile[q + 2], s[10]); atomicAdd(&tile[q + 3], s[11]); }
      if (mask & 8u) { int q = (ikey + 1025) * 4;
        atomicAdd(&tile[q], s[12]); atomicAdd(&tile[q + 1], s[13]);
        atomicAdd(&tile[q + 2], s[14]); atomicAdd(&tile[q + 3], s[15]); }
    }
  }
  __syncthreads();

  float4* dst = scratch + (size_t)blockIdx.x * TILE4;
  for (int i = tid; i < TILE4; i += 256) dst[i] = tile4[i];
}

// ============================================================ compose kernel
__global__ __launch_bounds__(256) void compose_k(const float4* __restrict__ scratch,
                                                 const u32* __restrict__ poff,
                                                 const float* __restrict__ meta,
                                                 float* __restrict__ out) {
  int p = blockIdx.x * 256 + threadIdx.x;
  if (p >= HWPIX) return;
  int y = p >> 10, x = p & 1023;
  int b = y >> 1, r = y & 1;
  float4 v = make_float4(0.f, 0.f, 0.f, 0.f);
  u32 k0 = poff[b], k1 = poff[b + 1];
  for (u32 k = k0; k < k1; ++k) {
    float4 a = scratch[(size_t)k * TILE4 + r * 1024 + x];
    v.x += a.x; v.y += a.y; v.z += a.z; v.w += a.w;
  }
  if (r == 0 && y > 0) {                  // halo row from band above
    u32 h0 = poff[b - 1], h1 = poff[b];
    for (u32 k = h0; k < h1; ++k) {
      float4 a = scratch[(size_t)k * TILE4 + 2 * 1024 + x];
      v.x += a.x; v.y += a.y; v.z += a.z; v.w += a.w;
    }
  }
  bool bf = meta[META_FLAG] != 0.0f;
  float nexp = bf ? 0.10009765625f : 0.1f;
  float denom = v.w + 1e-5f;
  float alpha = fminf(fmaxf(log1pf(v.w * nexp), 0.0f), 1.0f);
  float oma = 1.0f - alpha;
  out[p]             = sqrtf(fmaxf((v.x / denom) * alpha, 1e-8f)) + meta[META_BG + 0] * oma;
  out[HWPIX + p]     = sqrtf(fmaxf((v.y / denom) * alpha, 1e-8f)) + meta[META_BG + 1] * oma;
  out[2 * HWPIX + p] = sqrtf(fmaxf((v.z / denom) * alpha, 1e-8f)) + meta[META_BG + 2] * oma;
}

// ============================================================== scatter kernel
__global__ __launch_bounds__(256) void scatter_k(const uint2* __restrict__ recU,
                                                 uint2* __restrict__ recS,
                                                 const u32* __restrict__ counts,
                                                 const u32* __restrict__ starts) {
  __shared__ u32 cur[NBKT];
  int tid = threadIdx.x, blk = blockIdx.x;
  for (int b = tid; b < NBKT; b += 256) cur[b] = starts[b] + counts[b * NBLK + blk];
  __syncthreads();
  u32 n = (u32)blk * 256u + (u32)tid;
  for (int k = 0; k < NSPLAT; ++k) {
    uint2 r = recU[k * NP + n];
    if (r.y != 0xFFFFFFFFu) {
      int yi = (int)((r.y >> 11) & 0x7FFu) - 1;
      int yc = yi < 0 ? 0 : yi;
      u32 pos = atomicAdd(&cur[(u32)(yc >> 1)], 1u);
      recS[pos] = r;
    }
  }
}

// ================================================================= launcher
extern "C" void kernel_launch(void* const* d_in, const int* in_sizes, int n_in,
                              void* d_out, int out_size, void* d_ws, size_t ws_size,
                              hipStream_t stream) {
  (void)in_sizes; (void)n_in; (void)out_size; (void)ws_size;
  float4* scratch = (float4*)d_ws;                          // 2048*48KB = 96 MB
  uint2* recU = (uint2*)(scratch + (size_t)MAXWG * TILE4);  // 21 MB
  uint2* recS = recU + NREC;                                // 21 MB
  u32* counts = (u32*)(recS + NREC);                        // 512 KB
  u32* totals = counts + (size_t)NBKT * NBLK;
  u32* starts = totals + NBKT;                              // 513
  u32* poff   = starts + 520;                               // 513
  u32* wgmap  = poff + 520;                                 // 2048
  float* meta = (float*)(wgmap + MAXWG);

  setup_kernel<<<1, 64, 0, stream>>>(d_in[0], d_in[1], d_in[2], d_in[3], meta);
  chaos_record<<<NBLK, 256, 0, stream>>>(meta, recU, counts);
  pre_a<<<NBKT, 256, 0, stream>>>(counts, totals);
  pre_b<<<1, 512, 0, stream>>>(totals, starts);
  assign_k<<<1, 512, 0, stream>>>(starts, poff, wgmap);
  scatter_k<<<NBLK, 256, 0, stream>>>(recU, recS, counts, starts);
  accum_k<<<MAXWG, 256, 0, stream>>>(recS, starts, wgmap, meta, scratch);
  compose_k<<<(HWPIX + 255) / 256, 256, 0, stream>>>(scratch, poff, meta, (float*)d_out);
}

// Round 11
// 404.693 us; speedup vs baseline: 1.3281x; 1.3281x over previous
//
#include <hip/hip_runtime.h>
#include <hip/hip_bf16.h>
#include <math.h>

// ============================================================================
// Fractal-flame chaos game — bit-exact JAX RNG reproduction.
// R7: discrimination round. R5 (cache) null and R6 (wave combine) negative
// killed the same-address-serialization theory. This round: CHUNK 8192->2048
// (4x parallelism), 1-row bands (NBKT=1024), 32KB tiles (4 wgs/CU), direct
// LDS atomics (R4 baseline style). If accum scales ~1/4 => per-wg serial
// cost confirmed; if unchanged => shared-resource wall, pivot structure.
// ============================================================================

#define RNG_PARTITIONABLE 1
#define COLSUM_F32_ACCUM 1

typedef unsigned int u32;
typedef unsigned short u16;

static constexpr int FN = 8;
static constexpr int HH = 1024;
static constexpr int WW = 1024;
static constexpr int NP = 65536;
static constexpr int TI = 48;
static constexpr int WARM = 8;
static constexpr int HWPIX = HH * WW;
static constexpr int NSPLAT = TI - WARM;        // 40
static constexpr int NREC = NSPLAT * NP;        // 2,621,440
static constexpr int NBKT = 1024;               // 1-row full-width bands
static constexpr int NBLK = NP / 256;           // 256 chaos blocks
static constexpr u32 CHUNK = 2048;              // records per accum wg
static constexpr int MAXWG = 2560;              // bound: 1280 chunks + <=1024 partials
static constexpr int TILE4 = 2 * 1024;          // float4 cells per partial tile (32KB)

static constexpr int META_CUMPT = 0;    // 64 f32
static constexpr int META_AFF   = 64;   // 48 f32
static constexpr int META_CT    = 112;  // 24 f32
static constexpr int META_BG    = 136;  // 3 f32
static constexpr int META_FLAG  = 139;  // 1 f32
static constexpr int META_KEYS  = 140;  // 96 u32
static constexpr int META_KX    = 236;  // 2 u32
static constexpr int META_K2S   = 238;  // 2 u32

struct U2 { u32 x, y; };

// ---------------------------------------------------------------- threefry2x32
__device__ __forceinline__ U2 tf2x32(u32 k0, u32 k1, u32 c0, u32 c1) {
  u32 ks2 = k0 ^ k1 ^ 0x1BD11BDAu;
  u32 x0 = c0 + k0, x1 = c1 + k1;
#define TF_R(r) { x0 += x1; x1 = (x1 << (r)) | (x1 >> (32 - (r))); x1 ^= x0; }
  TF_R(13) TF_R(15) TF_R(26) TF_R(6)
  x0 += k1; x1 += ks2 + 1u;
  TF_R(17) TF_R(29) TF_R(16) TF_R(24)
  x0 += ks2; x1 += k0 + 2u;
  TF_R(13) TF_R(15) TF_R(26) TF_R(6)
  x0 += k0; x1 += k1 + 3u;
  TF_R(17) TF_R(29) TF_R(16) TF_R(24)
  x0 += k1; x1 += ks2 + 4u;
  TF_R(13) TF_R(15) TF_R(26) TF_R(6)
  x0 += ks2; x1 += k0 + 5u;
#undef TF_R
  return {x0, x1};
}

__device__ __forceinline__ u32 rbits(U2 key, u32 i, u32 halfN) {
#if RNG_PARTITIONABLE
  (void)halfN;
  U2 r = tf2x32(key.x, key.y, 0u, i);
  return r.x ^ r.y;
#else
  if (i < halfN) { U2 r = tf2x32(key.x, key.y, i, i + halfN); return r.x; }
  else           { U2 r = tf2x32(key.x, key.y, i - halfN, i); return r.y; }
#endif
}

__device__ __forceinline__ float unitf(u32 b) {  // jax uniform [0,1)
  return __uint_as_float((b >> 9) | 0x3F800000u) - 1.0f;
}

// ---------------------------------------------------------------- bf16 helpers
__device__ __forceinline__ float bf2f(u16 h) { return __uint_as_float(((u32)h) << 16); }
__device__ __forceinline__ float rndbf(float x) {
  u32 u = __float_as_uint(x);
  u32 r = (u + 0x7FFFu + ((u >> 16) & 1u)) & 0xFFFF0000u;
  return __uint_as_float(r);
}
__device__ __forceinline__ float rnd_m(float x, bool bf) { return bf ? rndbf(x) : x; }
__device__ __forceinline__ float ldf(const void* p, int i, bool bf) {
  return bf ? bf2f(((const u16*)p)[i]) : ((const float*)p)[i];
}
__device__ __forceinline__ float exp_cr(float x) { return (float)exp((double)x); }
__device__ __forceinline__ float sigchain(float x, bool bf) {
  float e = rnd_m(exp_cr(-x), bf);
  float d = rnd_m(1.0f + e, bf);
  return rnd_m(1.0f / d, bf);
}

// ============================================================== setup kernel
__global__ __launch_bounds__(64) void setup_kernel(const void* pn, const void* affp,
                                                   const void* ctp, const void* bgp,
                                                   float* meta) {
  __shared__ int vote;
  __shared__ float sP[64];
  __shared__ u32 sroot[8];
  int tid = threadIdx.x;
  if (tid == 0) vote = 0;
  __syncthreads();
  {
    float v = fabsf(bf2f(((const u16*)pn)[tid]));
    if (v > 1e-4f && v < 16.0f) atomicAdd(&vote, 1);
  }
  __syncthreads();
  bool bf = (vote >= 50);

  if (tid == 0) {
    meta[META_FLAG] = bf ? 1.0f : 0.0f;
    u32* mu = (u32*)meta;
#if RNG_PARTITIONABLE
    U2 kx = tf2x32(0u, 42u, 0u, 0u);
    U2 ks = tf2x32(0u, 42u, 0u, 1u);
    U2 kl = tf2x32(0u, 42u, 0u, 2u);
    U2 k2 = tf2x32(ks.x, ks.y, 0u, 1u);
#else
    U2 t0 = tf2x32(0u, 42u, 0u, 3u), t1 = tf2x32(0u, 42u, 1u, 4u), t2 = tf2x32(0u, 42u, 2u, 5u);
    U2 kx{t0.x, t1.x}, ks{t2.x, t0.y}, kl{t1.y, t2.y};
    U2 r0 = tf2x32(ks.x, ks.y, 0u, 2u), r1 = tf2x32(ks.x, ks.y, 1u, 3u);
    U2 k2{r0.y, r1.y};
#endif
    sroot[0] = kx.x; sroot[1] = kx.y; sroot[2] = ks.x; sroot[3] = ks.y;
    sroot[4] = kl.x; sroot[5] = kl.y; sroot[6] = k2.x; sroot[7] = k2.y;
    mu[META_KX] = kx.x; mu[META_KX + 1] = kx.y;
    mu[META_K2S] = k2.x; mu[META_K2S + 1] = k2.y;
  }

  float c001 = bf ? 0.00099945068359375f : 0.001f;
  sP[tid] = rnd_m(sigchain(ldf(pn, tid, bf), bf) + c001, bf);
  if (tid < 48) meta[META_AFF + tid] = ldf(affp, tid, bf);
  if (tid < 24) meta[META_CT + tid] = sigchain(ldf(ctp, tid, bf), bf);
  if (tid < 3)  meta[META_BG + tid] = sigchain(ldf(bgp, tid, bf), bf);
  __syncthreads();

  if (tid < 48) {
    U2 kl{sroot[4], sroot[5]};
    u32* mu = (u32*)meta;
#if RNG_PARTITIONABLE
    U2 kt = tf2x32(kl.x, kl.y, 0u, (u32)tid);
#else
    u32 e0 = 2u * tid, e1 = 2u * tid + 1u;
    u32 w0 = (e0 < 48u) ? tf2x32(kl.x, kl.y, e0, e0 + 48u).x : tf2x32(kl.x, kl.y, e0 - 48u, e0).y;
    u32 w1 = (e1 < 48u) ? tf2x32(kl.x, kl.y, e1, e1 + 48u).x : tf2x32(kl.x, kl.y, e1 - 48u, e1).y;
    U2 kt{w0, w1};
#endif
    mu[META_KEYS + 2 * tid]     = kt.x;
    mu[META_KEYS + 2 * tid + 1] = kt.y;
  }

  if (tid < 8) {
    int c = tid;
    float a[8];
#if COLSUM_F32_ACCUM
    float cs = 0.0f;
    for (int r = 0; r < 8; ++r) cs += sP[r * 8 + c];
    cs = rnd_m(cs, bf);
#else
    float cs = 0.0f;
    for (int r = 0; r < 8; ++r) cs = rnd_m(cs + sP[r * 8 + c], bf);
#endif
    for (int r = 0; r < 8; ++r) a[r] = rnd_m(sP[r * 8 + c] / cs, bf);
    float b0 = rnd_m(a[0] + a[1], bf), b1 = rnd_m(a[2] + a[3], bf);
    float b2 = rnd_m(a[4] + a[5], bf), b3 = rnd_m(a[6] + a[7], bf);
    float c0 = rnd_m(b0 + b1, bf), c1v = rnd_m(b2 + b3, bf);
    float d0 = rnd_m(c0 + c1v, bf);
    float s5 = rnd_m(c0 + b2, bf);
    float cum[8] = { a[0], b0, rnd_m(b0 + a[2], bf), c0,
                     rnd_m(c0 + a[4], bf), s5, rnd_m(s5 + a[6], bf), d0 };
    for (int r = 0; r < 8; ++r) meta[META_CUMPT + c * 8 + r] = cum[r];
  }
}

// ====================================================== chaos + record kernel
// 8B record: w0 = fxq<<16 | fyq; w1 = s<<22 | (yi+1)<<11 | (xi+1); ~0 invalid
__global__ __launch_bounds__(256) void chaos_record(const float* __restrict__ meta,
                                                    uint2* __restrict__ recU,
                                                    u32* __restrict__ counts) {
  __shared__ float cumPT[64];
  __shared__ float aff8[64];
  __shared__ u32 keyw[96];
  __shared__ u32 rk[4];
  __shared__ u32 cnt[NBKT];
  int tid = threadIdx.x;
  if (tid < 64) cumPT[tid] = meta[META_CUMPT + tid];
  if (tid < 48) aff8[(tid / 6) * 8 + (tid % 6)] = meta[META_AFF + tid];
  const u32* mu = (const u32*)meta;
  if (tid < 96) keyw[tid] = mu[META_KEYS + tid];
  if (tid < 4)  rk[tid] = mu[META_KX + tid];
  for (int b = tid; b < NBKT; b += 256) cnt[b] = 0u;
  __syncthreads();

  u32 n = blockIdx.x * 256u + (u32)tid;
  U2 kx{rk[0], rk[1]}, k2{rk[2], rk[3]};
  float x = fmaxf(-1.0f, unitf(rbits(kx, 2u * n,      65536u)) * 2.0f - 1.0f);
  float y = fmaxf(-1.0f, unitf(rbits(kx, 2u * n + 1u, 65536u)) * 2.0f - 1.0f);
  int s = (int)(rbits(k2, n, 32768u) & 7u);

  float uv[8];
  // warmup batch (no records)
#pragma unroll
  for (int j = 0; j < 8; ++j) {
    U2 kt{keyw[2 * j], keyw[2 * j + 1]};
    uv[j] = unitf(rbits(kt, n, 32768u));
  }
#pragma unroll
  for (int j = 0; j < 8; ++j) {
    float u = uv[j];
    float4 c0 = *(const float4*)&cumPT[s * 8];
    float4 c1 = *(const float4*)&cumPT[s * 8 + 4];
    int cntc = (c0.x < u) + (c0.y < u) + (c0.z < u) + (c0.w < u)
             + (c1.x < u) + (c1.y < u) + (c1.z < u) + (c1.w < u);
    int nxt = cntc < 7 ? cntc : 7;
    float4 A0 = *(const float4*)&aff8[nxt * 8];
    float4 A1 = *(const float4*)&aff8[nxt * 8 + 4];
    float xn = A0.x * x + A0.y * y + A0.z;
    float yn = A0.w * x + A1.x * y + A1.y;
    x = xn; y = yn; s = nxt;
  }

  for (int b = 1; b < 6; ++b) {
#pragma unroll
    for (int j = 0; j < 8; ++j) {
      U2 kt{keyw[16 * b + 2 * j], keyw[16 * b + 2 * j + 1]};
      uv[j] = unitf(rbits(kt, n, 32768u));
    }
#pragma unroll
    for (int j = 0; j < 8; ++j) {
      float u = uv[j];
      float4 c0 = *(const float4*)&cumPT[s * 8];
      float4 c1 = *(const float4*)&cumPT[s * 8 + 4];
      int cntc = (c0.x < u) + (c0.y < u) + (c0.z < u) + (c0.w < u)
               + (c1.x < u) + (c1.y < u) + (c1.z < u) + (c1.w < u);
      int nxt = cntc < 7 ? cntc : 7;
      float4 A0 = *(const float4*)&aff8[nxt * 8];
      float4 A1 = *(const float4*)&aff8[nxt * 8 + 4];
      float xn = A0.x * x + A0.y * y + A0.z;
      float yn = A0.w * x + A1.x * y + A1.y;
      x = xn; y = yn; s = nxt;

      float gx = (x + 1.0f) * 0.5f * 1024.0f - 0.5f;
      float gy = (y + 1.0f) * 0.5f * 1024.0f - 0.5f;
      float fx0 = floorf(gx), fy0 = floorf(gy);
      float fx = gx - fx0, fy = gy - fy0;
      int xi = (int)fx0, yi = (int)fy0;
      u32 w0 = 0u, w1 = 0xFFFFFFFFu;
      if (yi >= -1 && yi < 1024 && xi >= -1 && xi < 1024) {
        int yc = yi < 0 ? 0 : yi;
        u32 fxq = (u32)(fx * 65536.0f); if (fxq > 65535u) fxq = 65535u;
        u32 fyq = (u32)(fy * 65536.0f); if (fyq > 65535u) fyq = 65535u;
        w0 = (fxq << 16) | fyq;
        w1 = ((u32)s << 22) | ((u32)(yi + 1) << 11) | (u32)(xi + 1);
        atomicAdd(&cnt[(u32)yc], 1u);
      }
      recU[((b - 1) * 8 + j) * NP + n] = make_uint2(w0, w1);
    }
  }
  __syncthreads();
  for (int bb = tid; bb < NBKT; bb += 256) counts[bb * NBLK + blockIdx.x] = cnt[bb];
}

// ================================================== prefix kernels (counting sort)
__global__ __launch_bounds__(256) void pre_a(u32* __restrict__ counts,
                                             u32* __restrict__ totals) {
  int bkt = blockIdx.x, tid = threadIdx.x;
  __shared__ u32 sc[256];
  u32 v = counts[bkt * NBLK + tid];
  sc[tid] = v;
  __syncthreads();
  for (int off = 1; off < 256; off <<= 1) {
    u32 t = (tid >= off) ? sc[tid - off] : 0u;
    __syncthreads();
    sc[tid] += t;
    __syncthreads();
  }
  counts[bkt * NBLK + tid] = sc[tid] - v;     // exclusive within bucket
  if (tid == 255) totals[bkt] = sc[tid];
}

__global__ __launch_bounds__(1024) void pre_b(const u32* __restrict__ totals,
                                              u32* __restrict__ starts) {
  int tid = threadIdx.x;
  __shared__ u32 sc[NBKT];
  u32 v = totals[tid];
  sc[tid] = v;
  __syncthreads();
  for (int off = 1; off < NBKT; off <<= 1) {
    u32 t = (tid >= off) ? sc[tid - off] : 0u;
    __syncthreads();
    sc[tid] += t;
    __syncthreads();
  }
  starts[tid] = sc[tid] - v;
  if (tid == NBKT - 1) starts[NBKT] = sc[tid];
}

// =============================================== chunk assignment (equal work)
__global__ __launch_bounds__(1024) void assign_k(const u32* __restrict__ starts,
                                                 u32* __restrict__ poff,
                                                 u32* __restrict__ wgmap) {
  __shared__ u32 sc[NBKT];
  int tid = threadIdx.x;
  u32 len = starts[tid + 1] - starts[tid];
  u32 np = (len + CHUNK - 1) / CHUNK;           // 0 if empty
  sc[tid] = np;
  __syncthreads();
  for (int off = 1; off < NBKT; off <<= 1) {
    u32 t = (tid >= off) ? sc[tid - off] : 0u;
    __syncthreads();
    sc[tid] += t;
    __syncthreads();
  }
  u32 excl = sc[tid] - np;
  poff[tid] = excl;
  if (tid == NBKT - 1) poff[NBKT] = sc[tid];
  u32 total = sc[NBKT - 1];
  for (u32 j = 0; j < np; ++j) wgmap[excl + j] = ((u32)tid << 16) | j;
  for (u32 i = total + (u32)tid; i < (u32)MAXWG; i += (u32)NBKT) wgmap[i] = 0xFFFFFFFFu;
}

// ============================================================== scatter kernel
__global__ __launch_bounds__(256) void scatter_k(const uint2* __restrict__ recU,
                                                 uint2* __restrict__ recS,
                                                 const u32* __restrict__ counts,
                                                 const u32* __restrict__ starts) {
  __shared__ u32 cur[NBKT];
  int tid = threadIdx.x, blk = blockIdx.x;
  for (int b = tid; b < NBKT; b += 256) cur[b] = starts[b] + counts[b * NBLK + blk];
  __syncthreads();
  u32 n = (u32)blk * 256u + (u32)tid;
  for (int k = 0; k < NSPLAT; ++k) {
    uint2 r = recU[k * NP + n];
    if (r.y != 0xFFFFFFFFu) {
      int yi = (int)((r.y >> 11) & 0x7FFu) - 1;
      int yc = yi < 0 ? 0 : yi;
      u32 pos = atomicAdd(&cur[(u32)yc], 1u);
      recS[pos] = r;
    }
  }
}

// ================================= equal-work per-chunk LDS accumulation
// Direct atomics (R4 style). 1-row band: tile row 0 = own row b, row 1 = halo.
__global__ __launch_bounds__(256) void accum_k(const uint2* __restrict__ recS,
                                               const u32* __restrict__ starts,
                                               const u32* __restrict__ wgmap,
                                               const float* __restrict__ meta,
                                               float4* __restrict__ scratch) {
  u32 a = wgmap[blockIdx.x];
  if (a == 0xFFFFFFFFu) return;
  __shared__ float4 tile4[TILE4];               // 2 rows x 1024 cols, rgbw — 32 KB
  __shared__ float4 ctv[8];
  int tid = threadIdx.x;
  int b = (int)(a >> 16);
  u32 j = a & 0xFFFFu;
  u32 rs = starts[b] + j * CHUNK;
  u32 re = starts[b + 1];
  u32 rlim = rs + CHUNK;
  if (rlim < re) re = rlim;

  for (int i = tid; i < TILE4; i += 256) tile4[i] = make_float4(0.f, 0.f, 0.f, 0.f);
  if (tid < 8)
    ctv[tid] = make_float4(meta[META_CT + tid], meta[META_CT + 8 + tid],
                           meta[META_CT + 16 + tid], 1.0f);
  __syncthreads();

  float* tile = (float*)tile4;
  for (u32 i = rs + (u32)tid; i < re; i += 256u) {
    uint2 r = recS[i];
    int xi = (int)(r.y & 0x7FFu) - 1;
    int yi = (int)((r.y >> 11) & 0x7FFu) - 1;
    u32 sfn = (r.y >> 22) & 7u;
    float fx = (float)(r.x >> 16) * (1.0f / 65536.0f);
    float fy = (float)(r.x & 0xFFFFu) * (1.0f / 65536.0f);
    float ofx = 1.0f - fx, ofy = 1.0f - fy;
    float w00 = ofx * ofy, w10 = fx * ofy, w01 = ofx * fy, w11 = fx * fy;
    float4 cv = ctv[sfn];
    int ikey = (yi - b) * 1024 + xi;            // row 0 = own row (yi==b), or -1 row for yi<0
    bool y0ok = (u32)yi < 1024u, y1ok = (u32)(yi + 1) < 1024u;
    bool x0ok = (u32)xi < 1024u, x1ok = (u32)(xi + 1) < 1024u;
    if (y0ok && x0ok) { int q = ikey * 4;
      atomicAdd(&tile[q], w00 * cv.x); atomicAdd(&tile[q + 1], w00 * cv.y);
      atomicAdd(&tile[q + 2], w00 * cv.z); atomicAdd(&tile[q + 3], w00); }
    if (y0ok && x1ok) { int q = (ikey + 1) * 4;
      atomicAdd(&tile[q], w10 * cv.x); atomicAdd(&tile[q + 1], w10 * cv.y);
      atomicAdd(&tile[q + 2], w10 * cv.z); atomicAdd(&tile[q + 3], w10); }
    if (y1ok && x0ok) { int q = (ikey + 1024) * 4;
      atomicAdd(&tile[q], w01 * cv.x); atomicAdd(&tile[q + 1], w01 * cv.y);
      atomicAdd(&tile[q + 2], w01 * cv.z); atomicAdd(&tile[q + 3], w01); }
    if (y1ok && x1ok) { int q = (ikey + 1025) * 4;
      atomicAdd(&tile[q], w11 * cv.x); atomicAdd(&tile[q + 1], w11 * cv.y);
      atomicAdd(&tile[q + 2], w11 * cv.z); atomicAdd(&tile[q + 3], w11); }
  }
  __syncthreads();

  float4* dst = scratch + (size_t)blockIdx.x * TILE4;
  for (int i = tid; i < TILE4; i += 256) dst[i] = tile4[i];
}

// ============================================================ compose kernel
__global__ __launch_bounds__(256) void compose_k(const float4* __restrict__ scratch,
                                                 const u32* __restrict__ poff,
                                                 const float* __restrict__ meta,
                                                 float* __restrict__ out) {
  int p = blockIdx.x * 256 + threadIdx.x;
  if (p >= HWPIX) return;
  int y = p >> 10, x = p & 1023;
  float4 v = make_float4(0.f, 0.f, 0.f, 0.f);
  u32 k0 = poff[y], k1 = poff[y + 1];
  for (u32 k = k0; k < k1; ++k) {               // own band, row 0
    float4 a = scratch[(size_t)k * TILE4 + x];
    v.x += a.x; v.y += a.y; v.z += a.z; v.w += a.w;
  }
  if (y > 0) {                                  // band above, halo row 1
    u32 h0 = poff[y - 1], h1 = poff[y];
    for (u32 k = h0; k < h1; ++k) {
      float4 a = scratch[(size_t)k * TILE4 + 1024 + x];
      v.x += a.x; v.y += a.y; v.z += a.z; v.w += a.w;
    }
  }
  bool bf = meta[META_FLAG] != 0.0f;
  float nexp = bf ? 0.10009765625f : 0.1f;
  float denom = v.w + 1e-5f;
  float alpha = fminf(fmaxf(log1pf(v.w * nexp), 0.0f), 1.0f);
  float oma = 1.0f - alpha;
  out[p]             = sqrtf(fmaxf((v.x / denom) * alpha, 1e-8f)) + meta[META_BG + 0] * oma;
  out[HWPIX + p]     = sqrtf(fmaxf((v.y / denom) * alpha, 1e-8f)) + meta[META_BG + 1] * oma;
  out[2 * HWPIX + p] = sqrtf(fmaxf((v.z / denom) * alpha, 1e-8f)) + meta[META_BG + 2] * oma;
}

// ================================================================= launcher
extern "C" void kernel_launch(void* const* d_in, const int* in_sizes, int n_in,
                              void* d_out, int out_size, void* d_ws, size_t ws_size,
                              hipStream_t stream) {
  (void)in_sizes; (void)n_in; (void)out_size; (void)ws_size;
  float4* scratch = (float4*)d_ws;                          // 2560*32KB = 84 MB
  uint2* recU = (uint2*)(scratch + (size_t)MAXWG * TILE4);  // 21 MB
  uint2* recS = recU + NREC;                                // 21 MB
  u32* counts = (u32*)(recS + NREC);                        // 1024*256*4 = 1 MB
  u32* totals = counts + (size_t)NBKT * NBLK;               // 1024
  u32* starts = totals + NBKT;                              // 1025 (+pad)
  u32* poff   = starts + 1032;                              // 1025 (+pad)
  u32* wgmap  = poff + 1032;                                // 2560
  float* meta = (float*)(wgmap + MAXWG);

  setup_kernel<<<1, 64, 0, stream>>>(d_in[0], d_in[1], d_in[2], d_in[3], meta);
  chaos_record<<<NBLK, 256, 0, stream>>>(meta, recU, counts);
  pre_a<<<NBKT, 256, 0, stream>>>(counts, totals);
  pre_b<<<1, NBKT, 0, stream>>>(totals, starts);
  assign_k<<<1, NBKT, 0, stream>>>(starts, poff, wgmap);
  scatter_k<<<NBLK, 256, 0, stream>>>(recU, recS, counts, starts);
  accum_k<<<MAXWG, 256, 0, stream>>>(recS, starts, wgmap, meta, scratch);
  compose_k<<<(HWPIX + 255) / 256, 256, 0, stream>>>(scratch, poff, meta, (float*)d_out);
}

// Round 12
// 225.469 us; speedup vs baseline: 2.3838x; 1.7949x over previous
//
#include <hip/hip_runtime.h>
#include <hip/hip_bf16.h>
#include <math.h>

// ============================================================================
// Fractal-flame chaos game — bit-exact JAX RNG reproduction.
// R8: function-space LDS histogram. R5/R6/R7 triangulated the wall: per-CU
// LDS lane-atomic throughput (~4cyc/lane-RMW; 42M lane-ops => ~270us floor).
// Accumulate tile[row][col][fn] += w (4 atomics/record, not 16); apply the
// colour transform per-pixel in compose (linear => identical result modulo
// reassociation). Tile 2x1024x8 f32 = 64KB; everything else = R7.
// ============================================================================

#define RNG_PARTITIONABLE 1
#define COLSUM_F32_ACCUM 1

typedef unsigned int u32;
typedef unsigned short u16;

static constexpr int FN = 8;
static constexpr int HH = 1024;
static constexpr int WW = 1024;
static constexpr int NP = 65536;
static constexpr int TI = 48;
static constexpr int WARM = 8;
static constexpr int HWPIX = HH * WW;
static constexpr int NSPLAT = TI - WARM;        // 40
static constexpr int NREC = NSPLAT * NP;        // 2,621,440
static constexpr int NBKT = 1024;               // 1-row full-width bands
static constexpr int NBLK = NP / 256;           // 256 chaos blocks
static constexpr u32 CHUNK = 2048;              // records per accum wg
static constexpr int MAXWG = 2304;              // bound: 1280 + 1024 partial chunks
static constexpr int TILE_F = 2 * 1024 * 8;     // 16384 f32 = 64KB per partial
static constexpr int TILE_F4 = TILE_F / 4;      // 4096 float4

static constexpr int META_CUMPT = 0;    // 64 f32
static constexpr int META_AFF   = 64;   // 48 f32
static constexpr int META_CT    = 112;  // 24 f32
static constexpr int META_BG    = 136;  // 3 f32
static constexpr int META_FLAG  = 139;  // 1 f32
static constexpr int META_KEYS  = 140;  // 96 u32
static constexpr int META_KX    = 236;  // 2 u32
static constexpr int META_K2S   = 238;  // 2 u32

struct U2 { u32 x, y; };

// ---------------------------------------------------------------- threefry2x32
__device__ __forceinline__ U2 tf2x32(u32 k0, u32 k1, u32 c0, u32 c1) {
  u32 ks2 = k0 ^ k1 ^ 0x1BD11BDAu;
  u32 x0 = c0 + k0, x1 = c1 + k1;
#define TF_R(r) { x0 += x1; x1 = (x1 << (r)) | (x1 >> (32 - (r))); x1 ^= x0; }
  TF_R(13) TF_R(15) TF_R(26) TF_R(6)
  x0 += k1; x1 += ks2 + 1u;
  TF_R(17) TF_R(29) TF_R(16) TF_R(24)
  x0 += ks2; x1 += k0 + 2u;
  TF_R(13) TF_R(15) TF_R(26) TF_R(6)
  x0 += k0; x1 += k1 + 3u;
  TF_R(17) TF_R(29) TF_R(16) TF_R(24)
  x0 += k1; x1 += ks2 + 4u;
  TF_R(13) TF_R(15) TF_R(26) TF_R(6)
  x0 += ks2; x1 += k0 + 5u;
#undef TF_R
  return {x0, x1};
}

__device__ __forceinline__ u32 rbits(U2 key, u32 i, u32 halfN) {
#if RNG_PARTITIONABLE
  (void)halfN;
  U2 r = tf2x32(key.x, key.y, 0u, i);
  return r.x ^ r.y;
#else
  if (i < halfN) { U2 r = tf2x32(key.x, key.y, i, i + halfN); return r.x; }
  else           { U2 r = tf2x32(key.x, key.y, i - halfN, i); return r.y; }
#endif
}

__device__ __forceinline__ float unitf(u32 b) {  // jax uniform [0,1)
  return __uint_as_float((b >> 9) | 0x3F800000u) - 1.0f;
}

// ---------------------------------------------------------------- bf16 helpers
__device__ __forceinline__ float bf2f(u16 h) { return __uint_as_float(((u32)h) << 16); }
__device__ __forceinline__ float rndbf(float x) {
  u32 u = __float_as_uint(x);
  u32 r = (u + 0x7FFFu + ((u >> 16) & 1u)) & 0xFFFF0000u;
  return __uint_as_float(r);
}
__device__ __forceinline__ float rnd_m(float x, bool bf) { return bf ? rndbf(x) : x; }
__device__ __forceinline__ float ldf(const void* p, int i, bool bf) {
  return bf ? bf2f(((const u16*)p)[i]) : ((const float*)p)[i];
}
__device__ __forceinline__ float exp_cr(float x) { return (float)exp((double)x); }
__device__ __forceinline__ float sigchain(float x, bool bf) {
  float e = rnd_m(exp_cr(-x), bf);
  float d = rnd_m(1.0f + e, bf);
  return rnd_m(1.0f / d, bf);
}

// ============================================================== setup kernel
__global__ __launch_bounds__(64) void setup_kernel(const void* pn, const void* affp,
                                                   const void* ctp, const void* bgp,
                                                   float* meta) {
  __shared__ int vote;
  __shared__ float sP[64];
  __shared__ u32 sroot[8];
  int tid = threadIdx.x;
  if (tid == 0) vote = 0;
  __syncthreads();
  {
    float v = fabsf(bf2f(((const u16*)pn)[tid]));
    if (v > 1e-4f && v < 16.0f) atomicAdd(&vote, 1);
  }
  __syncthreads();
  bool bf = (vote >= 50);

  if (tid == 0) {
    meta[META_FLAG] = bf ? 1.0f : 0.0f;
    u32* mu = (u32*)meta;
#if RNG_PARTITIONABLE
    U2 kx = tf2x32(0u, 42u, 0u, 0u);
    U2 ks = tf2x32(0u, 42u, 0u, 1u);
    U2 kl = tf2x32(0u, 42u, 0u, 2u);
    U2 k2 = tf2x32(ks.x, ks.y, 0u, 1u);
#else
    U2 t0 = tf2x32(0u, 42u, 0u, 3u), t1 = tf2x32(0u, 42u, 1u, 4u), t2 = tf2x32(0u, 42u, 2u, 5u);
    U2 kx{t0.x, t1.x}, ks{t2.x, t0.y}, kl{t1.y, t2.y};
    U2 r0 = tf2x32(ks.x, ks.y, 0u, 2u), r1 = tf2x32(ks.x, ks.y, 1u, 3u);
    U2 k2{r0.y, r1.y};
#endif
    sroot[0] = kx.x; sroot[1] = kx.y; sroot[2] = ks.x; sroot[3] = ks.y;
    sroot[4] = kl.x; sroot[5] = kl.y; sroot[6] = k2.x; sroot[7] = k2.y;
    mu[META_KX] = kx.x; mu[META_KX + 1] = kx.y;
    mu[META_K2S] = k2.x; mu[META_K2S + 1] = k2.y;
  }

  float c001 = bf ? 0.00099945068359375f : 0.001f;
  sP[tid] = rnd_m(sigchain(ldf(pn, tid, bf), bf) + c001, bf);
  if (tid < 48) meta[META_AFF + tid] = ldf(affp, tid, bf);
  if (tid < 24) meta[META_CT + tid] = sigchain(ldf(ctp, tid, bf), bf);
  if (tid < 3)  meta[META_BG + tid] = sigchain(ldf(bgp, tid, bf), bf);
  __syncthreads();

  if (tid < 48) {
    U2 kl{sroot[4], sroot[5]};
    u32* mu = (u32*)meta;
#if RNG_PARTITIONABLE
    U2 kt = tf2x32(kl.x, kl.y, 0u, (u32)tid);
#else
    u32 e0 = 2u * tid, e1 = 2u * tid + 1u;
    u32 w0 = (e0 < 48u) ? tf2x32(kl.x, kl.y, e0, e0 + 48u).x : tf2x32(kl.x, kl.y, e0 - 48u, e0).y;
    u32 w1 = (e1 < 48u) ? tf2x32(kl.x, kl.y, e1, e1 + 48u).x : tf2x32(kl.x, kl.y, e1 - 48u, e1).y;
    U2 kt{w0, w1};
#endif
    mu[META_KEYS + 2 * tid]     = kt.x;
    mu[META_KEYS + 2 * tid + 1] = kt.y;
  }

  if (tid < 8) {
    int c = tid;
    float a[8];
#if COLSUM_F32_ACCUM
    float cs = 0.0f;
    for (int r = 0; r < 8; ++r) cs += sP[r * 8 + c];
    cs = rnd_m(cs, bf);
#else
    float cs = 0.0f;
    for (int r = 0; r < 8; ++r) cs = rnd_m(cs + sP[r * 8 + c], bf);
#endif
    for (int r = 0; r < 8; ++r) a[r] = rnd_m(sP[r * 8 + c] / cs, bf);
    float b0 = rnd_m(a[0] + a[1], bf), b1 = rnd_m(a[2] + a[3], bf);
    float b2 = rnd_m(a[4] + a[5], bf), b3 = rnd_m(a[6] + a[7], bf);
    float c0 = rnd_m(b0 + b1, bf), c1v = rnd_m(b2 + b3, bf);
    float d0 = rnd_m(c0 + c1v, bf);
    float s5 = rnd_m(c0 + b2, bf);
    float cum[8] = { a[0], b0, rnd_m(b0 + a[2], bf), c0,
                     rnd_m(c0 + a[4], bf), s5, rnd_m(s5 + a[6], bf), d0 };
    for (int r = 0; r < 8; ++r) meta[META_CUMPT + c * 8 + r] = cum[r];
  }
}

// ====================================================== chaos + record kernel
// 8B record: w0 = fxq<<16 | fyq; w1 = s<<22 | (yi+1)<<11 | (xi+1); ~0 invalid
__global__ __launch_bounds__(256) void chaos_record(const float* __restrict__ meta,
                                                    uint2* __restrict__ recU,
                                                    u32* __restrict__ counts) {
  __shared__ float cumPT[64];
  __shared__ float aff8[64];
  __shared__ u32 keyw[96];
  __shared__ u32 rk[4];
  __shared__ u32 cnt[NBKT];
  int tid = threadIdx.x;
  if (tid < 64) cumPT[tid] = meta[META_CUMPT + tid];
  if (tid < 48) aff8[(tid / 6) * 8 + (tid % 6)] = meta[META_AFF + tid];
  const u32* mu = (const u32*)meta;
  if (tid < 96) keyw[tid] = mu[META_KEYS + tid];
  if (tid < 4)  rk[tid] = mu[META_KX + tid];
  for (int b = tid; b < NBKT; b += 256) cnt[b] = 0u;
  __syncthreads();

  u32 n = blockIdx.x * 256u + (u32)tid;
  U2 kx{rk[0], rk[1]}, k2{rk[2], rk[3]};
  float x = fmaxf(-1.0f, unitf(rbits(kx, 2u * n,      65536u)) * 2.0f - 1.0f);
  float y = fmaxf(-1.0f, unitf(rbits(kx, 2u * n + 1u, 65536u)) * 2.0f - 1.0f);
  int s = (int)(rbits(k2, n, 32768u) & 7u);

  float uv[8];
  // warmup batch (no records)
#pragma unroll
  for (int j = 0; j < 8; ++j) {
    U2 kt{keyw[2 * j], keyw[2 * j + 1]};
    uv[j] = unitf(rbits(kt, n, 32768u));
  }
#pragma unroll
  for (int j = 0; j < 8; ++j) {
    float u = uv[j];
    float4 c0 = *(const float4*)&cumPT[s * 8];
    float4 c1 = *(const float4*)&cumPT[s * 8 + 4];
    int cntc = (c0.x < u) + (c0.y < u) + (c0.z < u) + (c0.w < u)
             + (c1.x < u) + (c1.y < u) + (c1.z < u) + (c1.w < u);
    int nxt = cntc < 7 ? cntc : 7;
    float4 A0 = *(const float4*)&aff8[nxt * 8];
    float4 A1 = *(const float4*)&aff8[nxt * 8 + 4];
    float xn = A0.x * x + A0.y * y + A0.z;
    float yn = A0.w * x + A1.x * y + A1.y;
    x = xn; y = yn; s = nxt;
  }

  for (int b = 1; b < 6; ++b) {
#pragma unroll
    for (int j = 0; j < 8; ++j) {
      U2 kt{keyw[16 * b + 2 * j], keyw[16 * b + 2 * j + 1]};
      uv[j] = unitf(rbits(kt, n, 32768u));
    }
#pragma unroll
    for (int j = 0; j < 8; ++j) {
      float u = uv[j];
      float4 c0 = *(const float4*)&cumPT[s * 8];
      float4 c1 = *(const float4*)&cumPT[s * 8 + 4];
      int cntc = (c0.x < u) + (c0.y < u) + (c0.z < u) + (c0.w < u)
               + (c1.x < u) + (c1.y < u) + (c1.z < u) + (c1.w < u);
      int nxt = cntc < 7 ? cntc : 7;
      float4 A0 = *(const float4*)&aff8[nxt * 8];
      float4 A1 = *(const float4*)&aff8[nxt * 8 + 4];
      float xn = A0.x * x + A0.y * y + A0.z;
      float yn = A0.w * x + A1.x * y + A1.y;
      x = xn; y = yn; s = nxt;

      float gx = (x + 1.0f) * 0.5f * 1024.0f - 0.5f;
      float gy = (y + 1.0f) * 0.5f * 1024.0f - 0.5f;
      float fx0 = floorf(gx), fy0 = floorf(gy);
      float fx = gx - fx0, fy = gy - fy0;
      int xi = (int)fx0, yi = (int)fy0;
      u32 w0 = 0u, w1 = 0xFFFFFFFFu;
      if (yi >= -1 && yi < 1024 && xi >= -1 && xi < 1024) {
        int yc = yi < 0 ? 0 : yi;
        u32 fxq = (u32)(fx * 65536.0f); if (fxq > 65535u) fxq = 65535u;
        u32 fyq = (u32)(fy * 65536.0f); if (fyq > 65535u) fyq = 65535u;
        w0 = (fxq << 16) | fyq;
        w1 = ((u32)s << 22) | ((u32)(yi + 1) << 11) | (u32)(xi + 1);
        atomicAdd(&cnt[(u32)yc], 1u);
      }
      recU[((b - 1) * 8 + j) * NP + n] = make_uint2(w0, w1);
    }
  }
  __syncthreads();
  for (int bb = tid; bb < NBKT; bb += 256) counts[bb * NBLK + blockIdx.x] = cnt[bb];
}

// ================================================== prefix kernels (counting sort)
__global__ __launch_bounds__(256) void pre_a(u32* __restrict__ counts,
                                             u32* __restrict__ totals) {
  int bkt = blockIdx.x, tid = threadIdx.x;
  __shared__ u32 sc[256];
  u32 v = counts[bkt * NBLK + tid];
  sc[tid] = v;
  __syncthreads();
  for (int off = 1; off < 256; off <<= 1) {
    u32 t = (tid >= off) ? sc[tid - off] : 0u;
    __syncthreads();
    sc[tid] += t;
    __syncthreads();
  }
  counts[bkt * NBLK + tid] = sc[tid] - v;     // exclusive within bucket
  if (tid == 255) totals[bkt] = sc[tid];
}

__global__ __launch_bounds__(1024) void pre_b(const u32* __restrict__ totals,
                                              u32* __restrict__ starts) {
  int tid = threadIdx.x;
  __shared__ u32 sc[NBKT];
  u32 v = totals[tid];
  sc[tid] = v;
  __syncthreads();
  for (int off = 1; off < NBKT; off <<= 1) {
    u32 t = (tid >= off) ? sc[tid - off] : 0u;
    __syncthreads();
    sc[tid] += t;
    __syncthreads();
  }
  starts[tid] = sc[tid] - v;
  if (tid == NBKT - 1) starts[NBKT] = sc[tid];
}

// =============================================== chunk assignment (equal work)
__global__ __launch_bounds__(1024) void assign_k(const u32* __restrict__ starts,
                                                 u32* __restrict__ poff,
                                                 u32* __restrict__ wgmap) {
  __shared__ u32 sc[NBKT];
  int tid = threadIdx.x;
  u32 len = starts[tid + 1] - starts[tid];
  u32 np = (len + CHUNK - 1) / CHUNK;           // 0 if empty
  sc[tid] = np;
  __syncthreads();
  for (int off = 1; off < NBKT; off <<= 1) {
    u32 t = (tid >= off) ? sc[tid - off] : 0u;
    __syncthreads();
    sc[tid] += t;
    __syncthreads();
  }
  u32 excl = sc[tid] - np;
  poff[tid] = excl;
  if (tid == NBKT - 1) poff[NBKT] = sc[tid];
  u32 total = sc[NBKT - 1];
  for (u32 j = 0; j < np; ++j) wgmap[excl + j] = ((u32)tid << 16) | j;
  for (u32 i = total + (u32)tid; i < (u32)MAXWG; i += (u32)NBKT) wgmap[i] = 0xFFFFFFFFu;
}

// ============================================================== scatter kernel
__global__ __launch_bounds__(256) void scatter_k(const uint2* __restrict__ recU,
                                                 uint2* __restrict__ recS,
                                                 const u32* __restrict__ counts,
                                                 const u32* __restrict__ starts) {
  __shared__ u32 cur[NBKT];
  int tid = threadIdx.x, blk = blockIdx.x;
  for (int b = tid; b < NBKT; b += 256) cur[b] = starts[b] + counts[b * NBLK + blk];
  __syncthreads();
  u32 n = (u32)blk * 256u + (u32)tid;
  for (int k = 0; k < NSPLAT; ++k) {
    uint2 r = recU[k * NP + n];
    if (r.y != 0xFFFFFFFFu) {
      int yi = (int)((r.y >> 11) & 0x7FFu) - 1;
      int yc = yi < 0 ? 0 : yi;
      u32 pos = atomicAdd(&cur[(u32)yc], 1u);
      recS[pos] = r;
    }
  }
}

// ================================= equal-work per-chunk LDS accumulation
// Function-space histogram: tile[row][col][fn] += w_corner — 4 LDS atomics
// per record (was 16). Row 0 = own band row b, row 1 = halo (b+1).
__global__ __launch_bounds__(256) void accum_k(const uint2* __restrict__ recS,
                                               const u32* __restrict__ starts,
                                               const u32* __restrict__ wgmap,
                                               float4* __restrict__ scratch) {
  u32 a = wgmap[blockIdx.x];
  if (a == 0xFFFFFFFFu) return;
  __shared__ float tile[TILE_F];                // 2 x 1024 x 8 f32 — 64 KB
  int tid = threadIdx.x;
  int b = (int)(a >> 16);
  u32 j = a & 0xFFFFu;
  u32 rs = starts[b] + j * CHUNK;
  u32 re = starts[b + 1];
  u32 rlim = rs + CHUNK;
  if (rlim < re) re = rlim;

  float4* t4 = (float4*)tile;
  for (int i = tid; i < TILE_F4; i += 256) t4[i] = make_float4(0.f, 0.f, 0.f, 0.f);
  __syncthreads();

  for (u32 i = rs + (u32)tid; i < re; i += 256u) {
    uint2 r = recS[i];
    int xi = (int)(r.y & 0x7FFu) - 1;
    int yi = (int)((r.y >> 11) & 0x7FFu) - 1;
    int sfn = (int)((r.y >> 22) & 7u);
    float fx = (float)(r.x >> 16) * (1.0f / 65536.0f);
    float fy = (float)(r.x & 0xFFFFu) * (1.0f / 65536.0f);
    float ofx = 1.0f - fx, ofy = 1.0f - fy;
    bool y0ok = (u32)yi < 1024u, y1ok = (u32)(yi + 1) < 1024u;
    bool x0ok = (u32)xi < 1024u, x1ok = (u32)(xi + 1) < 1024u;
    int base = ((yi - b) * 1024 + xi) * 8 + sfn;
    if (y0ok && x0ok) atomicAdd(&tile[base],        ofx * ofy);
    if (y0ok && x1ok) atomicAdd(&tile[base + 8],    fx * ofy);
    if (y1ok && x0ok) atomicAdd(&tile[base + 8192], ofx * fy);
    if (y1ok && x1ok) atomicAdd(&tile[base + 8200], fx * fy);
  }
  __syncthreads();

  float4* dst = scratch + (size_t)blockIdx.x * TILE_F4;
  for (int i = tid; i < TILE_F4; i += 256) dst[i] = t4[i];
}

// ============================================================ compose kernel
// Per pixel: sum 8 function channels over own-band partials (row 0) and the
// band-above's halo (row 1), then CT dot, log1p tone-map, gamma, background.
__global__ __launch_bounds__(256) void compose_k(const float4* __restrict__ scratch,
                                                 const u32* __restrict__ poff,
                                                 const float* __restrict__ meta,
                                                 float* __restrict__ out) {
  int p = blockIdx.x * 256 + threadIdx.x;
  if (p >= HWPIX) return;
  int y = p >> 10, x = p & 1023;
  float h[8];
#pragma unroll
  for (int f = 0; f < 8; ++f) h[f] = 0.0f;
  u32 k0 = poff[y], k1 = poff[y + 1];
  for (u32 k = k0; k < k1; ++k) {               // own band, row 0
    const float4* s = scratch + (size_t)k * TILE_F4 + x * 2;
    float4 a = s[0], b4 = s[1];
    h[0] += a.x; h[1] += a.y; h[2] += a.z; h[3] += a.w;
    h[4] += b4.x; h[5] += b4.y; h[6] += b4.z; h[7] += b4.w;
  }
  if (y > 0) {                                  // band above, halo row 1
    u32 g0 = poff[y - 1], g1 = poff[y];
    for (u32 k = g0; k < g1; ++k) {
      const float4* s = scratch + (size_t)k * TILE_F4 + 2048 + x * 2;
      float4 a = s[0], b4 = s[1];
      h[0] += a.x; h[1] += a.y; h[2] += a.z; h[3] += a.w;
      h[4] += b4.x; h[5] += b4.y; h[6] += b4.z; h[7] += b4.w;
    }
  }
  float hs = 0.0f;
#pragma unroll
  for (int f = 0; f < 8; ++f) hs += h[f];
  bool bf = meta[META_FLAG] != 0.0f;
  float nexp = bf ? 0.10009765625f : 0.1f;
  float denom = hs + 1e-5f;
  float alpha = fminf(fmaxf(log1pf(hs * nexp), 0.0f), 1.0f);
  float oma = 1.0f - alpha;
#pragma unroll
  for (int c = 0; c < 3; ++c) {
    float rgb = 0.0f;
#pragma unroll
    for (int f = 0; f < 8; ++f) rgb += meta[META_CT + c * 8 + f] * h[f];
    out[(size_t)c * HWPIX + p] =
        sqrtf(fmaxf((rgb / denom) * alpha, 1e-8f)) + meta[META_BG + c] * oma;
  }
}

// ================================================================= launcher
extern "C" void kernel_launch(void* const* d_in, const int* in_sizes, int n_in,
                              void* d_out, int out_size, void* d_ws, size_t ws_size,
                              hipStream_t stream) {
  (void)in_sizes; (void)n_in; (void)out_size; (void)ws_size;
  float4* scratch = (float4*)d_ws;                            // 2304*64KB = 147 MB
  uint2* recU = (uint2*)(scratch + (size_t)MAXWG * TILE_F4);  // 21 MB
  uint2* recS = recU + NREC;                                  // 21 MB
  u32* counts = (u32*)(recS + NREC);                          // 1 MB
  u32* totals = counts + (size_t)NBKT * NBLK;                 // 1024
  u32* starts = totals + NBKT;                                // 1025 (+pad)
  u32* poff   = starts + 1032;                                // 1025 (+pad)
  u32* wgmap  = poff + 1032;                                  // 2304
  float* meta = (float*)(wgmap + MAXWG);

  setup_kernel<<<1, 64, 0, stream>>>(d_in[0], d_in[1], d_in[2], d_in[3], meta);
  chaos_record<<<NBLK, 256, 0, stream>>>(meta, recU, counts);
  pre_a<<<NBKT, 256, 0, stream>>>(counts, totals);
  pre_b<<<1, NBKT, 0, stream>>>(totals, starts);
  assign_k<<<1, NBKT, 0, stream>>>(starts, poff, wgmap);
  scatter_k<<<NBLK, 256, 0, stream>>>(recU, recS, counts, starts);
  accum_k<<<MAXWG, 256, 0, stream>>>(recS, starts, wgmap, scratch);
  compose_k<<<(HWPIX + 255) / 256, 256, 0, stream>>>(scratch, poff, meta, (float*)d_out);
}

// Round 13
// 225.295 us; speedup vs baseline: 2.3856x; 1.0008x over previous
//
#include <hip/hip_runtime.h>
#include <hip/hip_bf16.h>
#include <math.h>

// ============================================================================
// Fractal-flame chaos game — bit-exact JAX RNG reproduction.
// R9: R8's function-space LDS histogram (validated: 4 atomics/record, accum
// 78us) + pipeline cuts: (1) two-pass trajectory (count, then replay+direct
// sorted write) replaces record+scatter — trajectory is deterministic so
// replay is bit-identical; (2) CHUNK 4096 halves partial-tile flush/compose
// traffic; (3) pre_b+assign fused. 7 launches, ~130 MB ws.
// ============================================================================

#define RNG_PARTITIONABLE 1
#define COLSUM_F32_ACCUM 1

typedef unsigned int u32;
typedef unsigned short u16;

static constexpr int FN = 8;
static constexpr int HH = 1024;
static constexpr int WW = 1024;
static constexpr int NP = 65536;
static constexpr int TI = 48;
static constexpr int WARM = 8;
static constexpr int HWPIX = HH * WW;
static constexpr int NSPLAT = TI - WARM;        // 40
static constexpr int NREC = NSPLAT * NP;        // 2,621,440
static constexpr int NBKT = 1024;               // 1-row full-width bands
static constexpr int NBLK = NP / 256;           // 256 chaos blocks
static constexpr u32 CHUNK = 4096;              // records per accum wg
static constexpr int MAXWG = 1664;              // 640 full + <=1024 partial chunks
static constexpr int TILE_F = 2 * 1024 * 8;     // 16384 f32 = 64KB per partial
static constexpr int TILE_F4 = TILE_F / 4;      // 4096 float4

static constexpr int META_CUMPT = 0;    // 64 f32
static constexpr int META_AFF   = 64;   // 48 f32
static constexpr int META_CT    = 112;  // 24 f32
static constexpr int META_BG    = 136;  // 3 f32
static constexpr int META_FLAG  = 139;  // 1 f32
static constexpr int META_KEYS  = 140;  // 96 u32
static constexpr int META_KX    = 236;  // 2 u32
static constexpr int META_K2S   = 238;  // 2 u32

struct U2 { u32 x, y; };

// ---------------------------------------------------------------- threefry2x32
__device__ __forceinline__ U2 tf2x32(u32 k0, u32 k1, u32 c0, u32 c1) {
  u32 ks2 = k0 ^ k1 ^ 0x1BD11BDAu;
  u32 x0 = c0 + k0, x1 = c1 + k1;
#define TF_R(r) { x0 += x1; x1 = (x1 << (r)) | (x1 >> (32 - (r))); x1 ^= x0; }
  TF_R(13) TF_R(15) TF_R(26) TF_R(6)
  x0 += k1; x1 += ks2 + 1u;
  TF_R(17) TF_R(29) TF_R(16) TF_R(24)
  x0 += ks2; x1 += k0 + 2u;
  TF_R(13) TF_R(15) TF_R(26) TF_R(6)
  x0 += k0; x1 += k1 + 3u;
  TF_R(17) TF_R(29) TF_R(16) TF_R(24)
  x0 += k1; x1 += ks2 + 4u;
  TF_R(13) TF_R(15) TF_R(26) TF_R(6)
  x0 += ks2; x1 += k0 + 5u;
#undef TF_R
  return {x0, x1};
}

__device__ __forceinline__ u32 rbits(U2 key, u32 i, u32 halfN) {
#if RNG_PARTITIONABLE
  (void)halfN;
  U2 r = tf2x32(key.x, key.y, 0u, i);
  return r.x ^ r.y;
#else
  if (i < halfN) { U2 r = tf2x32(key.x, key.y, i, i + halfN); return r.x; }
  else           { U2 r = tf2x32(key.x, key.y, i - halfN, i); return r.y; }
#endif
}

__device__ __forceinline__ float unitf(u32 b) {  // jax uniform [0,1)
  return __uint_as_float((b >> 9) | 0x3F800000u) - 1.0f;
}

// ---------------------------------------------------------------- bf16 helpers
__device__ __forceinline__ float bf2f(u16 h) { return __uint_as_float(((u32)h) << 16); }
__device__ __forceinline__ float rndbf(float x) {
  u32 u = __float_as_uint(x);
  u32 r = (u + 0x7FFFu + ((u >> 16) & 1u)) & 0xFFFF0000u;
  return __uint_as_float(r);
}
__device__ __forceinline__ float rnd_m(float x, bool bf) { return bf ? rndbf(x) : x; }
__device__ __forceinline__ float ldf(const void* p, int i, bool bf) {
  return bf ? bf2f(((const u16*)p)[i]) : ((const float*)p)[i];
}
__device__ __forceinline__ float exp_cr(float x) { return (float)exp((double)x); }
__device__ __forceinline__ float sigchain(float x, bool bf) {
  float e = rnd_m(exp_cr(-x), bf);
  float d = rnd_m(1.0f + e, bf);
  return rnd_m(1.0f / d, bf);
}

// ============================================================== setup kernel
__global__ __launch_bounds__(64) void setup_kernel(const void* pn, const void* affp,
                                                   const void* ctp, const void* bgp,
                                                   float* meta) {
  __shared__ int vote;
  __shared__ float sP[64];
  __shared__ u32 sroot[8];
  int tid = threadIdx.x;
  if (tid == 0) vote = 0;
  __syncthreads();
  {
    float v = fabsf(bf2f(((const u16*)pn)[tid]));
    if (v > 1e-4f && v < 16.0f) atomicAdd(&vote, 1);
  }
  __syncthreads();
  bool bf = (vote >= 50);

  if (tid == 0) {
    meta[META_FLAG] = bf ? 1.0f : 0.0f;
    u32* mu = (u32*)meta;
#if RNG_PARTITIONABLE
    U2 kx = tf2x32(0u, 42u, 0u, 0u);
    U2 ks = tf2x32(0u, 42u, 0u, 1u);
    U2 kl = tf2x32(0u, 42u, 0u, 2u);
    U2 k2 = tf2x32(ks.x, ks.y, 0u, 1u);
#else
    U2 t0 = tf2x32(0u, 42u, 0u, 3u), t1 = tf2x32(0u, 42u, 1u, 4u), t2 = tf2x32(0u, 42u, 2u, 5u);
    U2 kx{t0.x, t1.x}, ks{t2.x, t0.y}, kl{t1.y, t2.y};
    U2 r0 = tf2x32(ks.x, ks.y, 0u, 2u), r1 = tf2x32(ks.x, ks.y, 1u, 3u);
    U2 k2{r0.y, r1.y};
#endif
    sroot[0] = kx.x; sroot[1] = kx.y; sroot[2] = ks.x; sroot[3] = ks.y;
    sroot[4] = kl.x; sroot[5] = kl.y; sroot[6] = k2.x; sroot[7] = k2.y;
    mu[META_KX] = kx.x; mu[META_KX + 1] = kx.y;
    mu[META_K2S] = k2.x; mu[META_K2S + 1] = k2.y;
  }

  float c001 = bf ? 0.00099945068359375f : 0.001f;
  sP[tid] = rnd_m(sigchain(ldf(pn, tid, bf), bf) + c001, bf);
  if (tid < 48) meta[META_AFF + tid] = ldf(affp, tid, bf);
  if (tid < 24) meta[META_CT + tid] = sigchain(ldf(ctp, tid, bf), bf);
  if (tid < 3)  meta[META_BG + tid] = sigchain(ldf(bgp, tid, bf), bf);
  __syncthreads();

  if (tid < 48) {
    U2 kl{sroot[4], sroot[5]};
    u32* mu = (u32*)meta;
#if RNG_PARTITIONABLE
    U2 kt = tf2x32(kl.x, kl.y, 0u, (u32)tid);
#else
    u32 e0 = 2u * tid, e1 = 2u * tid + 1u;
    u32 w0 = (e0 < 48u) ? tf2x32(kl.x, kl.y, e0, e0 + 48u).x : tf2x32(kl.x, kl.y, e0 - 48u, e0).y;
    u32 w1 = (e1 < 48u) ? tf2x32(kl.x, kl.y, e1, e1 + 48u).x : tf2x32(kl.x, kl.y, e1 - 48u, e1).y;
    U2 kt{w0, w1};
#endif
    mu[META_KEYS + 2 * tid]     = kt.x;
    mu[META_KEYS + 2 * tid + 1] = kt.y;
  }

  if (tid < 8) {
    int c = tid;
    float a[8];
#if COLSUM_F32_ACCUM
    float cs = 0.0f;
    for (int r = 0; r < 8; ++r) cs += sP[r * 8 + c];
    cs = rnd_m(cs, bf);
#else
    float cs = 0.0f;
    for (int r = 0; r < 8; ++r) cs = rnd_m(cs + sP[r * 8 + c], bf);
#endif
    for (int r = 0; r < 8; ++r) a[r] = rnd_m(sP[r * 8 + c] / cs, bf);
    float b0 = rnd_m(a[0] + a[1], bf), b1 = rnd_m(a[2] + a[3], bf);
    float b2 = rnd_m(a[4] + a[5], bf), b3 = rnd_m(a[6] + a[7], bf);
    float c0 = rnd_m(b0 + b1, bf), c1v = rnd_m(b2 + b3, bf);
    float d0 = rnd_m(c0 + c1v, bf);
    float s5 = rnd_m(c0 + b2, bf);
    float cum[8] = { a[0], b0, rnd_m(b0 + a[2], bf), c0,
                     rnd_m(c0 + a[4], bf), s5, rnd_m(s5 + a[6], bf), d0 };
    for (int r = 0; r < 8; ++r) meta[META_CUMPT + c * 8 + r] = cum[r];
  }
}

// ======================= trajectory body (shared by count & scatter passes)
// EMIT(j_global, gx, gy, xi, yi, s) called for each of the 40 recorded splats.
#define TRAJ_BODY(EMIT)                                                        \
  u32 n = blockIdx.x * 256u + (u32)tid;                                        \
  U2 kx{rk[0], rk[1]}, k2{rk[2], rk[3]};                                       \
  float x = fmaxf(-1.0f, unitf(rbits(kx, 2u * n,      65536u)) * 2.0f - 1.0f); \
  float y = fmaxf(-1.0f, unitf(rbits(kx, 2u * n + 1u, 65536u)) * 2.0f - 1.0f); \
  int s = (int)(rbits(k2, n, 32768u) & 7u);                                    \
  float uv[8];                                                                 \
  _Pragma("unroll")                                                            \
  for (int j = 0; j < 8; ++j) {                                                \
    U2 kt{keyw[2 * j], keyw[2 * j + 1]};                                       \
    uv[j] = unitf(rbits(kt, n, 32768u));                                       \
  }                                                                            \
  _Pragma("unroll")                                                            \
  for (int j = 0; j < 8; ++j) {                                                \
    float u = uv[j];                                                           \
    float4 c0 = *(const float4*)&cumPT[s * 8];                                 \
    float4 c1 = *(const float4*)&cumPT[s * 8 + 4];                             \
    int cntc = (c0.x < u) + (c0.y < u) + (c0.z < u) + (c0.w < u)               \
             + (c1.x < u) + (c1.y < u) + (c1.z < u) + (c1.w < u);              \
    int nxt = cntc < 7 ? cntc : 7;                                             \
    float4 A0 = *(const float4*)&aff8[nxt * 8];                                \
    float4 A1 = *(const float4*)&aff8[nxt * 8 + 4];                            \
    float xn = A0.x * x + A0.y * y + A0.z;                                     \
    float yn = A0.w * x + A1.x * y + A1.y;                                     \
    x = xn; y = yn; s = nxt;                                                   \
  }                                                                            \
  for (int b = 1; b < 6; ++b) {                                                \
    _Pragma("unroll")                                                          \
    for (int j = 0; j < 8; ++j) {                                              \
      U2 kt{keyw[16 * b + 2 * j], keyw[16 * b + 2 * j + 1]};                   \
      uv[j] = unitf(rbits(kt, n, 32768u));                                     \
    }                                                                          \
    _Pragma("unroll")                                                          \
    for (int j = 0; j < 8; ++j) {                                              \
      float u = uv[j];                                                         \
      float4 c0 = *(const float4*)&cumPT[s * 8];                               \
      float4 c1 = *(const float4*)&cumPT[s * 8 + 4];                           \
      int cntc = (c0.x < u) + (c0.y < u) + (c0.z < u) + (c0.w < u)             \
               + (c1.x < u) + (c1.y < u) + (c1.z < u) + (c1.w < u);            \
      int nxt = cntc < 7 ? cntc : 7;                                           \
      float4 A0 = *(const float4*)&aff8[nxt * 8];                              \
      float4 A1 = *(const float4*)&aff8[nxt * 8 + 4];                          \
      float xn = A0.x * x + A0.y * y + A0.z;                                   \
      float yn = A0.w * x + A1.x * y + A1.y;                                   \
      x = xn; y = yn; s = nxt;                                                 \
      float gx = (x + 1.0f) * 0.5f * 1024.0f - 0.5f;                           \
      float gy = (y + 1.0f) * 0.5f * 1024.0f - 0.5f;                           \
      float fx0 = floorf(gx), fy0 = floorf(gy);                                \
      float fx = gx - fx0, fy = gy - fy0;                                      \
      int xi = (int)fx0, yi = (int)fy0;                                        \
      EMIT                                                                     \
    }                                                                          \
  }

// ====================================================== pass 1: count
__global__ __launch_bounds__(256) void chaos_count(const float* __restrict__ meta,
                                                   u32* __restrict__ counts) {
  __shared__ float cumPT[64];
  __shared__ float aff8[64];
  __shared__ u32 keyw[96];
  __shared__ u32 rk[4];
  __shared__ u32 cnt[NBKT];
  int tid = threadIdx.x;
  if (tid < 64) cumPT[tid] = meta[META_CUMPT + tid];
  if (tid < 48) aff8[(tid / 6) * 8 + (tid % 6)] = meta[META_AFF + tid];
  const u32* mu = (const u32*)meta;
  if (tid < 96) keyw[tid] = mu[META_KEYS + tid];
  if (tid < 4)  rk[tid] = mu[META_KX + tid];
  for (int b = tid; b < NBKT; b += 256) cnt[b] = 0u;
  __syncthreads();

  TRAJ_BODY({
    (void)fx; (void)fy;
    if (yi >= -1 && yi < 1024 && xi >= -1 && xi < 1024) {
      int yc = yi < 0 ? 0 : yi;
      atomicAdd(&cnt[(u32)yc], 1u);
    }
  })
  __syncthreads();
  for (int bb = tid; bb < NBKT; bb += 256) counts[bb * NBLK + blockIdx.x] = cnt[bb];
}

// ================================================== prefix kernels (counting sort)
__global__ __launch_bounds__(256) void pre_a(u32* __restrict__ counts,
                                             u32* __restrict__ totals) {
  int bkt = blockIdx.x, tid = threadIdx.x;
  __shared__ u32 sc[256];
  u32 v = counts[bkt * NBLK + tid];
  sc[tid] = v;
  __syncthreads();
  for (int off = 1; off < 256; off <<= 1) {
    u32 t = (tid >= off) ? sc[tid - off] : 0u;
    __syncthreads();
    sc[tid] += t;
    __syncthreads();
  }
  counts[bkt * NBLK + tid] = sc[tid] - v;     // exclusive within bucket
  if (tid == 255) totals[bkt] = sc[tid];
}

// fused: starts-scan + chunk assignment
__global__ __launch_bounds__(1024) void pre_ba(const u32* __restrict__ totals,
                                               u32* __restrict__ starts,
                                               u32* __restrict__ poff,
                                               u32* __restrict__ wgmap) {
  __shared__ u32 sc[NBKT];
  int tid = threadIdx.x;
  u32 v = totals[tid];
  sc[tid] = v;
  __syncthreads();
  for (int off = 1; off < NBKT; off <<= 1) {
    u32 t = (tid >= off) ? sc[tid - off] : 0u;
    __syncthreads();
    sc[tid] += t;
    __syncthreads();
  }
  starts[tid] = sc[tid] - v;
  if (tid == NBKT - 1) starts[NBKT] = sc[tid];
  __syncthreads();
  u32 np = (v + CHUNK - 1) / CHUNK;             // 0 if empty
  sc[tid] = np;
  __syncthreads();
  for (int off = 1; off < NBKT; off <<= 1) {
    u32 t = (tid >= off) ? sc[tid - off] : 0u;
    __syncthreads();
    sc[tid] += t;
    __syncthreads();
  }
  u32 excl = sc[tid] - np;
  poff[tid] = excl;
  if (tid == NBKT - 1) poff[NBKT] = sc[tid];
  u32 total = sc[NBKT - 1];
  for (u32 j = 0; j < np; ++j) wgmap[excl + j] = ((u32)tid << 16) | j;
  for (u32 i = total + (u32)tid; i < (u32)MAXWG; i += (u32)NBKT) wgmap[i] = 0xFFFFFFFFu;
}

// ====================================================== pass 2: replay + scatter
// 8B record: w0 = fxq<<16 | fyq; w1 = s<<22 | (yi+1)<<11 | (xi+1)
__global__ __launch_bounds__(256) void chaos_scatter(const float* __restrict__ meta,
                                                     const u32* __restrict__ counts,
                                                     const u32* __restrict__ starts,
                                                     uint2* __restrict__ recS) {
  __shared__ float cumPT[64];
  __shared__ float aff8[64];
  __shared__ u32 keyw[96];
  __shared__ u32 rk[4];
  __shared__ u32 cur[NBKT];
  int tid = threadIdx.x;
  if (tid < 64) cumPT[tid] = meta[META_CUMPT + tid];
  if (tid < 48) aff8[(tid / 6) * 8 + (tid % 6)] = meta[META_AFF + tid];
  const u32* mu = (const u32*)meta;
  if (tid < 96) keyw[tid] = mu[META_KEYS + tid];
  if (tid < 4)  rk[tid] = mu[META_KX + tid];
  for (int b = tid; b < NBKT; b += 256) cur[b] = starts[b] + counts[b * NBLK + blockIdx.x];
  __syncthreads();

  TRAJ_BODY({
    if (yi >= -1 && yi < 1024 && xi >= -1 && xi < 1024) {
      int yc = yi < 0 ? 0 : yi;
      u32 fxq = (u32)(fx * 65536.0f); if (fxq > 65535u) fxq = 65535u;
      u32 fyq = (u32)(fy * 65536.0f); if (fyq > 65535u) fyq = 65535u;
      u32 pos = atomicAdd(&cur[(u32)yc], 1u);
      recS[pos] = make_uint2((fxq << 16) | fyq,
                             ((u32)s << 22) | ((u32)(yi + 1) << 11) | (u32)(xi + 1));
    }
  })
}

// ================================= equal-work per-chunk LDS accumulation
// Function-space histogram: tile[row][col][fn] += w_corner — 4 LDS atomics
// per record. Row 0 = own band row b, row 1 = halo (b+1).
__global__ __launch_bounds__(256) void accum_k(const uint2* __restrict__ recS,
                                               const u32* __restrict__ starts,
                                               const u32* __restrict__ wgmap,
                                               float4* __restrict__ scratch) {
  u32 a = wgmap[blockIdx.x];
  if (a == 0xFFFFFFFFu) return;
  __shared__ float tile[TILE_F];                // 2 x 1024 x 8 f32 — 64 KB
  int tid = threadIdx.x;
  int b = (int)(a >> 16);
  u32 j = a & 0xFFFFu;
  u32 rs = starts[b] + j * CHUNK;
  u32 re = starts[b + 1];
  u32 rlim = rs + CHUNK;
  if (rlim < re) re = rlim;

  float4* t4 = (float4*)tile;
  for (int i = tid; i < TILE_F4; i += 256) t4[i] = make_float4(0.f, 0.f, 0.f, 0.f);
  __syncthreads();

  for (u32 i = rs + (u32)tid; i < re; i += 256u) {
    uint2 r = recS[i];
    int xi = (int)(r.y & 0x7FFu) - 1;
    int yi = (int)((r.y >> 11) & 0x7FFu) - 1;
    int sfn = (int)((r.y >> 22) & 7u);
    float fx = (float)(r.x >> 16) * (1.0f / 65536.0f);
    float fy = (float)(r.x & 0xFFFFu) * (1.0f / 65536.0f);
    float ofx = 1.0f - fx, ofy = 1.0f - fy;
    bool y0ok = (u32)yi < 1024u, y1ok = (u32)(yi + 1) < 1024u;
    bool x0ok = (u32)xi < 1024u, x1ok = (u32)(xi + 1) < 1024u;
    int base = ((yi - b) * 1024 + xi) * 8 + sfn;
    if (y0ok && x0ok) atomicAdd(&tile[base],        ofx * ofy);
    if (y0ok && x1ok) atomicAdd(&tile[base + 8],    fx * ofy);
    if (y1ok && x0ok) atomicAdd(&tile[base + 8192], ofx * fy);
    if (y1ok && x1ok) atomicAdd(&tile[base + 8200], fx * fy);
  }
  __syncthreads();

  float4* dst = scratch + (size_t)blockIdx.x * TILE_F4;
  for (int i = tid; i < TILE_F4; i += 256) dst[i] = t4[i];
}

// ============================================================ compose kernel
__global__ __launch_bounds__(256) void compose_k(const float4* __restrict__ scratch,
                                                 const u32* __restrict__ poff,
                                                 const float* __restrict__ meta,
                                                 float* __restrict__ out) {
  int p = blockIdx.x * 256 + threadIdx.x;
  if (p >= HWPIX) return;
  int y = p >> 10, x = p & 1023;
  float h[8];
#pragma unroll
  for (int f = 0; f < 8; ++f) h[f] = 0.0f;
  u32 k0 = poff[y], k1 = poff[y + 1];
  for (u32 k = k0; k < k1; ++k) {               // own band, row 0
    const float4* s = scratch + (size_t)k * TILE_F4 + x * 2;
    float4 a = s[0], b4 = s[1];
    h[0] += a.x; h[1] += a.y; h[2] += a.z; h[3] += a.w;
    h[4] += b4.x; h[5] += b4.y; h[6] += b4.z; h[7] += b4.w;
  }
  if (y > 0) {                                  // band above, halo row 1
    u32 g0 = poff[y - 1], g1 = poff[y];
    for (u32 k = g0; k < g1; ++k) {
      const float4* s = scratch + (size_t)k * TILE_F4 + 2048 + x * 2;
      float4 a = s[0], b4 = s[1];
      h[0] += a.x; h[1] += a.y; h[2] += a.z; h[3] += a.w;
      h[4] += b4.x; h[5] += b4.y; h[6] += b4.z; h[7] += b4.w;
    }
  }
  float hs = 0.0f;
#pragma unroll
  for (int f = 0; f < 8; ++f) hs += h[f];
  bool bf = meta[META_FLAG] != 0.0f;
  float nexp = bf ? 0.10009765625f : 0.1f;
  float denom = hs + 1e-5f;
  float alpha = fminf(fmaxf(log1pf(hs * nexp), 0.0f), 1.0f);
  float oma = 1.0f - alpha;
#pragma unroll
  for (int c = 0; c < 3; ++c) {
    float rgb = 0.0f;
#pragma unroll
    for (int f = 0; f < 8; ++f) rgb += meta[META_CT + c * 8 + f] * h[f];
    out[(size_t)c * HWPIX + p] =
        sqrtf(fmaxf((rgb / denom) * alpha, 1e-8f)) + meta[META_BG + c] * oma;
  }
}

// ================================================================= launcher
extern "C" void kernel_launch(void* const* d_in, const int* in_sizes, int n_in,
                              void* d_out, int out_size, void* d_ws, size_t ws_size,
                              hipStream_t stream) {
  (void)in_sizes; (void)n_in; (void)out_size; (void)ws_size;
  float4* scratch = (float4*)d_ws;                            // 1664*64KB = 104 MB
  uint2* recS = (uint2*)(scratch + (size_t)MAXWG * TILE_F4);  // 21 MB
  u32* counts = (u32*)(recS + NREC);                          // 1 MB
  u32* totals = counts + (size_t)NBKT * NBLK;                 // 1024
  u32* starts = totals + NBKT;                                // 1025 (+pad)
  u32* poff   = starts + 1032;                                // 1025 (+pad)
  u32* wgmap  = poff + 1032;                                  // 1664
  float* meta = (float*)(wgmap + MAXWG);

  setup_kernel<<<1, 64, 0, stream>>>(d_in[0], d_in[1], d_in[2], d_in[3], meta);
  chaos_count<<<NBLK, 256, 0, stream>>>(meta, counts);
  pre_a<<<NBKT, 256, 0, stream>>>(counts, totals);
  pre_ba<<<1, NBKT, 0, stream>>>(totals, starts, poff, wgmap);
  chaos_scatter<<<NBLK, 256, 0, stream>>>(meta, counts, starts, recS);
  accum_k<<<MAXWG, 256, 0, stream>>>(recS, starts, wgmap, scratch);
  compose_k<<<(HWPIX + 255) / 256, 256, 0, stream>>>(scratch, poff, meta, (float*)d_out);
}

// Round 14
// 221.709 us; speedup vs baseline: 2.4242x; 1.0162x over previous
//
#include <hip/hip_runtime.h>
#include <hip/hip_bf16.h>
#include <math.h>

// ============================================================================
// Fractal-flame chaos game — bit-exact JAX RNG reproduction.
// R10: R9 + latency fix in accum_k. R9 evidence: 625 cyc/record-iteration at
// 13.6% occupancy = serial dependent loads (~300-600cy each), not DS
// throughput. Fix: batch-load all 8 records/thread upfront (independent
// loads, one latency round-trip), 512-thread blocks (16 waves/CU at 64KB
// LDS) for TLP. Everything else identical to R9.
// ============================================================================

#define RNG_PARTITIONABLE 1
#define COLSUM_F32_ACCUM 1

typedef unsigned int u32;
typedef unsigned short u16;

static constexpr int FN = 8;
static constexpr int HH = 1024;
static constexpr int WW = 1024;
static constexpr int NP = 65536;
static constexpr int TI = 48;
static constexpr int WARM = 8;
static constexpr int HWPIX = HH * WW;
static constexpr int NSPLAT = TI - WARM;        // 40
static constexpr int NREC = NSPLAT * NP;        // 2,621,440
static constexpr int NBKT = 1024;               // 1-row full-width bands
static constexpr int NBLK = NP / 256;           // 256 chaos blocks
static constexpr u32 CHUNK = 4096;              // records per accum wg
static constexpr int MAXWG = 1664;              // 640 full + <=1024 partial chunks
static constexpr int TILE_F = 2 * 1024 * 8;     // 16384 f32 = 64KB per partial
static constexpr int TILE_F4 = TILE_F / 4;      // 4096 float4
static constexpr int ABLK = 512;                // accum block size
static constexpr int RPT = (int)(CHUNK / ABLK); // 8 records per thread

static constexpr int META_CUMPT = 0;    // 64 f32
static constexpr int META_AFF   = 64;   // 48 f32
static constexpr int META_CT    = 112;  // 24 f32
static constexpr int META_BG    = 136;  // 3 f32
static constexpr int META_FLAG  = 139;  // 1 f32
static constexpr int META_KEYS  = 140;  // 96 u32
static constexpr int META_KX    = 236;  // 2 u32
static constexpr int META_K2S   = 238;  // 2 u32

struct U2 { u32 x, y; };

// ---------------------------------------------------------------- threefry2x32
__device__ __forceinline__ U2 tf2x32(u32 k0, u32 k1, u32 c0, u32 c1) {
  u32 ks2 = k0 ^ k1 ^ 0x1BD11BDAu;
  u32 x0 = c0 + k0, x1 = c1 + k1;
#define TF_R(r) { x0 += x1; x1 = (x1 << (r)) | (x1 >> (32 - (r))); x1 ^= x0; }
  TF_R(13) TF_R(15) TF_R(26) TF_R(6)
  x0 += k1; x1 += ks2 + 1u;
  TF_R(17) TF_R(29) TF_R(16) TF_R(24)
  x0 += ks2; x1 += k0 + 2u;
  TF_R(13) TF_R(15) TF_R(26) TF_R(6)
  x0 += k0; x1 += k1 + 3u;
  TF_R(17) TF_R(29) TF_R(16) TF_R(24)
  x0 += k1; x1 += ks2 + 4u;
  TF_R(13) TF_R(15) TF_R(26) TF_R(6)
  x0 += ks2; x1 += k0 + 5u;
#undef TF_R
  return {x0, x1};
}

__device__ __forceinline__ u32 rbits(U2 key, u32 i, u32 halfN) {
#if RNG_PARTITIONABLE
  (void)halfN;
  U2 r = tf2x32(key.x, key.y, 0u, i);
  return r.x ^ r.y;
#else
  if (i < halfN) { U2 r = tf2x32(key.x, key.y, i, i + halfN); return r.x; }
  else           { U2 r = tf2x32(key.x, key.y, i - halfN, i); return r.y; }
#endif
}

__device__ __forceinline__ float unitf(u32 b) {  // jax uniform [0,1)
  return __uint_as_float((b >> 9) | 0x3F800000u) - 1.0f;
}

// ---------------------------------------------------------------- bf16 helpers
__device__ __forceinline__ float bf2f(u16 h) { return __uint_as_float(((u32)h) << 16); }
__device__ __forceinline__ float rndbf(float x) {
  u32 u = __float_as_uint(x);
  u32 r = (u + 0x7FFFu + ((u >> 16) & 1u)) & 0xFFFF0000u;
  return __uint_as_float(r);
}
__device__ __forceinline__ float rnd_m(float x, bool bf) { return bf ? rndbf(x) : x; }
__device__ __forceinline__ float ldf(const void* p, int i, bool bf) {
  return bf ? bf2f(((const u16*)p)[i]) : ((const float*)p)[i];
}
__device__ __forceinline__ float exp_cr(float x) { return (float)exp((double)x); }
__device__ __forceinline__ float sigchain(float x, bool bf) {
  float e = rnd_m(exp_cr(-x), bf);
  float d = rnd_m(1.0f + e, bf);
  return rnd_m(1.0f / d, bf);
}

// ============================================================== setup kernel
__global__ __launch_bounds__(64) void setup_kernel(const void* pn, const void* affp,
                                                   const void* ctp, const void* bgp,
                                                   float* meta) {
  __shared__ int vote;
  __shared__ float sP[64];
  __shared__ u32 sroot[8];
  int tid = threadIdx.x;
  if (tid == 0) vote = 0;
  __syncthreads();
  {
    float v = fabsf(bf2f(((const u16*)pn)[tid]));
    if (v > 1e-4f && v < 16.0f) atomicAdd(&vote, 1);
  }
  __syncthreads();
  bool bf = (vote >= 50);

  if (tid == 0) {
    meta[META_FLAG] = bf ? 1.0f : 0.0f;
    u32* mu = (u32*)meta;
#if RNG_PARTITIONABLE
    U2 kx = tf2x32(0u, 42u, 0u, 0u);
    U2 ks = tf2x32(0u, 42u, 0u, 1u);
    U2 kl = tf2x32(0u, 42u, 0u, 2u);
    U2 k2 = tf2x32(ks.x, ks.y, 0u, 1u);
#else
    U2 t0 = tf2x32(0u, 42u, 0u, 3u), t1 = tf2x32(0u, 42u, 1u, 4u), t2 = tf2x32(0u, 42u, 2u, 5u);
    U2 kx{t0.x, t1.x}, ks{t2.x, t0.y}, kl{t1.y, t2.y};
    U2 r0 = tf2x32(ks.x, ks.y, 0u, 2u), r1 = tf2x32(ks.x, ks.y, 1u, 3u);
    U2 k2{r0.y, r1.y};
#endif
    sroot[0] = kx.x; sroot[1] = kx.y; sroot[2] = ks.x; sroot[3] = ks.y;
    sroot[4] = kl.x; sroot[5] = kl.y; sroot[6] = k2.x; sroot[7] = k2.y;
    mu[META_KX] = kx.x; mu[META_KX + 1] = kx.y;
    mu[META_K2S] = k2.x; mu[META_K2S + 1] = k2.y;
  }

  float c001 = bf ? 0.00099945068359375f : 0.001f;
  sP[tid] = rnd_m(sigchain(ldf(pn, tid, bf), bf) + c001, bf);
  if (tid < 48) meta[META_AFF + tid] = ldf(affp, tid, bf);
  if (tid < 24) meta[META_CT + tid] = sigchain(ldf(ctp, tid, bf), bf);
  if (tid < 3)  meta[META_BG + tid] = sigchain(ldf(bgp, tid, bf), bf);
  __syncthreads();

  if (tid < 48) {
    U2 kl{sroot[4], sroot[5]};
    u32* mu = (u32*)meta;
#if RNG_PARTITIONABLE
    U2 kt = tf2x32(kl.x, kl.y, 0u, (u32)tid);
#else
    u32 e0 = 2u * tid, e1 = 2u * tid + 1u;
    u32 w0 = (e0 < 48u) ? tf2x32(kl.x, kl.y, e0, e0 + 48u).x : tf2x32(kl.x, kl.y, e0 - 48u, e0).y;
    u32 w1 = (e1 < 48u) ? tf2x32(kl.x, kl.y, e1, e1 + 48u).x : tf2x32(kl.x, kl.y, e1 - 48u, e1).y;
    U2 kt{w0, w1};
#endif
    mu[META_KEYS + 2 * tid]     = kt.x;
    mu[META_KEYS + 2 * tid + 1] = kt.y;
  }

  if (tid < 8) {
    int c = tid;
    float a[8];
#if COLSUM_F32_ACCUM
    float cs = 0.0f;
    for (int r = 0; r < 8; ++r) cs += sP[r * 8 + c];
    cs = rnd_m(cs, bf);
#else
    float cs = 0.0f;
    for (int r = 0; r < 8; ++r) cs = rnd_m(cs + sP[r * 8 + c], bf);
#endif
    for (int r = 0; r < 8; ++r) a[r] = rnd_m(sP[r * 8 + c] / cs, bf);
    float b0 = rnd_m(a[0] + a[1], bf), b1 = rnd_m(a[2] + a[3], bf);
    float b2 = rnd_m(a[4] + a[5], bf), b3 = rnd_m(a[6] + a[7], bf);
    float c0 = rnd_m(b0 + b1, bf), c1v = rnd_m(b2 + b3, bf);
    float d0 = rnd_m(c0 + c1v, bf);
    float s5 = rnd_m(c0 + b2, bf);
    float cum[8] = { a[0], b0, rnd_m(b0 + a[2], bf), c0,
                     rnd_m(c0 + a[4], bf), s5, rnd_m(s5 + a[6], bf), d0 };
    for (int r = 0; r < 8; ++r) meta[META_CUMPT + c * 8 + r] = cum[r];
  }
}

// ======================= trajectory body (shared by count & scatter passes)
#define TRAJ_BODY(EMIT)                                                        \
  u32 n = blockIdx.x * 256u + (u32)tid;                                        \
  U2 kx{rk[0], rk[1]}, k2{rk[2], rk[3]};                                       \
  float x = fmaxf(-1.0f, unitf(rbits(kx, 2u * n,      65536u)) * 2.0f - 1.0f); \
  float y = fmaxf(-1.0f, unitf(rbits(kx, 2u * n + 1u, 65536u)) * 2.0f - 1.0f); \
  int s = (int)(rbits(k2, n, 32768u) & 7u);                                    \
  float uv[8];                                                                 \
  _Pragma("unroll")                                                            \
  for (int j = 0; j < 8; ++j) {                                                \
    U2 kt{keyw[2 * j], keyw[2 * j + 1]};                                       \
    uv[j] = unitf(rbits(kt, n, 32768u));                                       \
  }                                                                            \
  _Pragma("unroll")                                                            \
  for (int j = 0; j < 8; ++j) {                                                \
    float u = uv[j];                                                           \
    float4 c0 = *(const float4*)&cumPT[s * 8];                                 \
    float4 c1 = *(const float4*)&cumPT[s * 8 + 4];                             \
    int cntc = (c0.x < u) + (c0.y < u) + (c0.z < u) + (c0.w < u)               \
             + (c1.x < u) + (c1.y < u) + (c1.z < u) + (c1.w < u);              \
    int nxt = cntc < 7 ? cntc : 7;                                             \
    float4 A0 = *(const float4*)&aff8[nxt * 8];                                \
    float4 A1 = *(const float4*)&aff8[nxt * 8 + 4];                            \
    float xn = A0.x * x + A0.y * y + A0.z;                                     \
    float yn = A0.w * x + A1.x * y + A1.y;                                     \
    x = xn; y = yn; s = nxt;                                                   \
  }                                                                            \
  for (int b = 1; b < 6; ++b) {                                                \
    _Pragma("unroll")                                                          \
    for (int j = 0; j < 8; ++j) {                                              \
      U2 kt{keyw[16 * b + 2 * j], keyw[16 * b + 2 * j + 1]};                   \
      uv[j] = unitf(rbits(kt, n, 32768u));                                     \
    }                                                                          \
    _Pragma("unroll")                                                          \
    for (int j = 0; j < 8; ++j) {                                              \
      float u = uv[j];                                                         \
      float4 c0 = *(const float4*)&cumPT[s * 8];                               \
      float4 c1 = *(const float4*)&cumPT[s * 8 + 4];                           \
      int cntc = (c0.x < u) + (c0.y < u) + (c0.z < u) + (c0.w < u)             \
               + (c1.x < u) + (c1.y < u) + (c1.z < u) + (c1.w < u);            \
      int nxt = cntc < 7 ? cntc : 7;                                           \
      float4 A0 = *(const float4*)&aff8[nxt * 8];                              \
      float4 A1 = *(const float4*)&aff8[nxt * 8 + 4];                          \
      float xn = A0.x * x + A0.y * y + A0.z;                                   \
      float yn = A0.w * x + A1.x * y + A1.y;                                   \
      x = xn; y = yn; s = nxt;                                                 \
      float gx = (x + 1.0f) * 0.5f * 1024.0f - 0.5f;                           \
      float gy = (y + 1.0f) * 0.5f * 1024.0f - 0.5f;                           \
      float fx0 = floorf(gx), fy0 = floorf(gy);                                \
      float fx = gx - fx0, fy = gy - fy0;                                      \
      int xi = (int)fx0, yi = (int)fy0;                                        \
      EMIT                                                                     \
    }                                                                          \
  }

// ====================================================== pass 1: count
__global__ __launch_bounds__(256) void chaos_count(const float* __restrict__ meta,
                                                   u32* __restrict__ counts) {
  __shared__ float cumPT[64];
  __shared__ float aff8[64];
  __shared__ u32 keyw[96];
  __shared__ u32 rk[4];
  __shared__ u32 cnt[NBKT];
  int tid = threadIdx.x;
  if (tid < 64) cumPT[tid] = meta[META_CUMPT + tid];
  if (tid < 48) aff8[(tid / 6) * 8 + (tid % 6)] = meta[META_AFF + tid];
  const u32* mu = (const u32*)meta;
  if (tid < 96) keyw[tid] = mu[META_KEYS + tid];
  if (tid < 4)  rk[tid] = mu[META_KX + tid];
  for (int b = tid; b < NBKT; b += 256) cnt[b] = 0u;
  __syncthreads();

  TRAJ_BODY({
    (void)fx; (void)fy;
    if (yi >= -1 && yi < 1024 && xi >= -1 && xi < 1024) {
      int yc = yi < 0 ? 0 : yi;
      atomicAdd(&cnt[(u32)yc], 1u);
    }
  })
  __syncthreads();
  for (int bb = tid; bb < NBKT; bb += 256) counts[bb * NBLK + blockIdx.x] = cnt[bb];
}

// ================================================== prefix kernels (counting sort)
__global__ __launch_bounds__(256) void pre_a(u32* __restrict__ counts,
                                             u32* __restrict__ totals) {
  int bkt = blockIdx.x, tid = threadIdx.x;
  __shared__ u32 sc[256];
  u32 v = counts[bkt * NBLK + tid];
  sc[tid] = v;
  __syncthreads();
  for (int off = 1; off < 256; off <<= 1) {
    u32 t = (tid >= off) ? sc[tid - off] : 0u;
    __syncthreads();
    sc[tid] += t;
    __syncthreads();
  }
  counts[bkt * NBLK + tid] = sc[tid] - v;     // exclusive within bucket
  if (tid == 255) totals[bkt] = sc[tid];
}

// fused: starts-scan + chunk assignment
__global__ __launch_bounds__(1024) void pre_ba(const u32* __restrict__ totals,
                                               u32* __restrict__ starts,
                                               u32* __restrict__ poff,
                                               u32* __restrict__ wgmap) {
  __shared__ u32 sc[NBKT];
  int tid = threadIdx.x;
  u32 v = totals[tid];
  sc[tid] = v;
  __syncthreads();
  for (int off = 1; off < NBKT; off <<= 1) {
    u32 t = (tid >= off) ? sc[tid - off] : 0u;
    __syncthreads();
    sc[tid] += t;
    __syncthreads();
  }
  starts[tid] = sc[tid] - v;
  if (tid == NBKT - 1) starts[NBKT] = sc[tid];
  __syncthreads();
  u32 np = (v + CHUNK - 1) / CHUNK;             // 0 if empty
  sc[tid] = np;
  __syncthreads();
  for (int off = 1; off < NBKT; off <<= 1) {
    u32 t = (tid >= off) ? sc[tid - off] : 0u;
    __syncthreads();
    sc[tid] += t;
    __syncthreads();
  }
  u32 excl = sc[tid] - np;
  poff[tid] = excl;
  if (tid == NBKT - 1) poff[NBKT] = sc[tid];
  u32 total = sc[NBKT - 1];
  for (u32 j = 0; j < np; ++j) wgmap[excl + j] = ((u32)tid << 16) | j;
  for (u32 i = total + (u32)tid; i < (u32)MAXWG; i += (u32)NBKT) wgmap[i] = 0xFFFFFFFFu;
}

// ====================================================== pass 2: replay + scatter
// 8B record: w0 = fxq<<16 | fyq; w1 = s<<22 | (yi+1)<<11 | (xi+1)
__global__ __launch_bounds__(256) void chaos_scatter(const float* __restrict__ meta,
                                                     const u32* __restrict__ counts,
                                                     const u32* __restrict__ starts,
                                                     uint2* __restrict__ recS) {
  __shared__ float cumPT[64];
  __shared__ float aff8[64];
  __shared__ u32 keyw[96];
  __shared__ u32 rk[4];
  __shared__ u32 cur[NBKT];
  int tid = threadIdx.x;
  if (tid < 64) cumPT[tid] = meta[META_CUMPT + tid];
  if (tid < 48) aff8[(tid / 6) * 8 + (tid % 6)] = meta[META_AFF + tid];
  const u32* mu = (const u32*)meta;
  if (tid < 96) keyw[tid] = mu[META_KEYS + tid];
  if (tid < 4)  rk[tid] = mu[META_KX + tid];
  for (int b = tid; b < NBKT; b += 256) cur[b] = starts[b] + counts[b * NBLK + blockIdx.x];
  __syncthreads();

  TRAJ_BODY({
    if (yi >= -1 && yi < 1024 && xi >= -1 && xi < 1024) {
      int yc = yi < 0 ? 0 : yi;
      u32 fxq = (u32)(fx * 65536.0f); if (fxq > 65535u) fxq = 65535u;
      u32 fyq = (u32)(fy * 65536.0f); if (fyq > 65535u) fyq = 65535u;
      u32 pos = atomicAdd(&cur[(u32)yc], 1u);
      recS[pos] = make_uint2((fxq << 16) | fyq,
                             ((u32)s << 22) | ((u32)(yi + 1) << 11) | (u32)(xi + 1));
    }
  })
}

// ================================= equal-work per-chunk LDS accumulation
// Function-space histogram, batch-loaded: all RPT records/thread loaded
// upfront (independent loads => one latency round-trip), then decode + 4
// fire-and-forget ds_adds each. 512-thread blocks => ~16 waves/CU at 64KB.
__global__ __launch_bounds__(ABLK) void accum_k(const uint2* __restrict__ recS,
                                                const u32* __restrict__ starts,
                                                const u32* __restrict__ wgmap,
                                                float4* __restrict__ scratch) {
  u32 a = wgmap[blockIdx.x];
  if (a == 0xFFFFFFFFu) return;
  __shared__ float tile[TILE_F];                // 2 x 1024 x 8 f32 — 64 KB
  int tid = threadIdx.x;
  int b = (int)(a >> 16);
  u32 j = a & 0xFFFFu;
  u32 rs = starts[b] + j * CHUNK;
  u32 re = starts[b + 1];
  u32 rlim = rs + CHUNK;
  if (rlim < re) re = rlim;

  float4* t4 = (float4*)tile;
  for (int i = tid; i < TILE_F4; i += ABLK) t4[i] = make_float4(0.f, 0.f, 0.f, 0.f);

  // batch-load all records for this thread (independent, pipelined loads)
  uint2 rec[RPT];
  u32 base = rs + (u32)tid;
#pragma unroll
  for (int t = 0; t < RPT; ++t) {
    u32 idx = base + (u32)(t * ABLK);
    rec[t] = (idx < re) ? recS[idx]
                        : make_uint2(0u, 0xFFFFFFFFu);  // decodes all-OOB
  }
  __syncthreads();

#pragma unroll
  for (int t = 0; t < RPT; ++t) {
    uint2 r = rec[t];
    int xi = (int)(r.y & 0x7FFu) - 1;
    int yi = (int)((r.y >> 11) & 0x7FFu) - 1;
    int sfn = (int)((r.y >> 22) & 7u);
    float fx = (float)(r.x >> 16) * (1.0f / 65536.0f);
    float fy = (float)(r.x & 0xFFFFu) * (1.0f / 65536.0f);
    float ofx = 1.0f - fx, ofy = 1.0f - fy;
    bool y0ok = (u32)yi < 1024u, y1ok = (u32)(yi + 1) < 1024u;
    bool x0ok = (u32)xi < 1024u, x1ok = (u32)(xi + 1) < 1024u;
    int base2 = ((yi - b) * 1024 + xi) * 8 + sfn;
    if (y0ok && x0ok) atomicAdd(&tile[base2],        ofx * ofy);
    if (y0ok && x1ok) atomicAdd(&tile[base2 + 8],    fx * ofy);
    if (y1ok && x0ok) atomicAdd(&tile[base2 + 8192], ofx * fy);
    if (y1ok && x1ok) atomicAdd(&tile[base2 + 8200], fx * fy);
  }
  __syncthreads();

  float4* dst = scratch + (size_t)blockIdx.x * TILE_F4;
  for (int i = tid; i < TILE_F4; i += ABLK) dst[i] = t4[i];
}

// ============================================================ compose kernel
__global__ __launch_bounds__(256) void compose_k(const float4* __restrict__ scratch,
                                                 const u32* __restrict__ poff,
                                                 const float* __restrict__ meta,
                                                 float* __restrict__ out) {
  int p = blockIdx.x * 256 + threadIdx.x;
  if (p >= HWPIX) return;
  int y = p >> 10, x = p & 1023;
  float h[8];
#pragma unroll
  for (int f = 0; f < 8; ++f) h[f] = 0.0f;
  u32 k0 = poff[y], k1 = poff[y + 1];
  for (u32 k = k0; k < k1; ++k) {               // own band, row 0
    const float4* s = scratch + (size_t)k * TILE_F4 + x * 2;
    float4 a = s[0], b4 = s[1];
    h[0] += a.x; h[1] += a.y; h[2] += a.z; h[3] += a.w;
    h[4] += b4.x; h[5] += b4.y; h[6] += b4.z; h[7] += b4.w;
  }
  if (y > 0) {                                  // band above, halo row 1
    u32 g0 = poff[y - 1], g1 = poff[y];
    for (u32 k = g0; k < g1; ++k) {
      const float4* s = scratch + (size_t)k * TILE_F4 + 2048 + x * 2;
      float4 a = s[0], b4 = s[1];
      h[0] += a.x; h[1] += a.y; h[2] += a.z; h[3] += a.w;
      h[4] += b4.x; h[5] += b4.y; h[6] += b4.z; h[7] += b4.w;
    }
  }
  float hs = 0.0f;
#pragma unroll
  for (int f = 0; f < 8; ++f) hs += h[f];
  bool bf = meta[META_FLAG] != 0.0f;
  float nexp = bf ? 0.10009765625f : 0.1f;
  float denom = hs + 1e-5f;
  float alpha = fminf(fmaxf(log1pf(hs * nexp), 0.0f), 1.0f);
  float oma = 1.0f - alpha;
#pragma unroll
  for (int c = 0; c < 3; ++c) {
    float rgb = 0.0f;
#pragma unroll
    for (int f = 0; f < 8; ++f) rgb += meta[META_CT + c * 8 + f] * h[f];
    out[(size_t)c * HWPIX + p] =
        sqrtf(fmaxf((rgb / denom) * alpha, 1e-8f)) + meta[META_BG + c] * oma;
  }
}

// ================================================================= launcher
extern "C" void kernel_launch(void* const* d_in, const int* in_sizes, int n_in,
                              void* d_out, int out_size, void* d_ws, size_t ws_size,
                              hipStream_t stream) {
  (void)in_sizes; (void)n_in; (void)out_size; (void)ws_size;
  float4* scratch = (float4*)d_ws;                            // 1664*64KB = 104 MB
  uint2* recS = (uint2*)(scratch + (size_t)MAXWG * TILE_F4);  // 21 MB
  u32* counts = (u32*)(recS + NREC);                          // 1 MB
  u32* totals = counts + (size_t)NBKT * NBLK;                 // 1024
  u32* starts = totals + NBKT;                                // 1025 (+pad)
  u32* poff   = starts + 1032;                                // 1025 (+pad)
  u32* wgmap  = poff + 1032;                                  // 1664
  float* meta = (float*)(wgmap + MAXWG);

  setup_kernel<<<1, 64, 0, stream>>>(d_in[0], d_in[1], d_in[2], d_in[3], meta);
  chaos_count<<<NBLK, 256, 0, stream>>>(meta, counts);
  pre_a<<<NBKT, 256, 0, stream>>>(counts, totals);
  pre_ba<<<1, NBKT, 0, stream>>>(totals, starts, poff, wgmap);
  chaos_scatter<<<NBLK, 256, 0, stream>>>(meta, counts, starts, recS);
  accum_k<<<MAXWG, ABLK, 0, stream>>>(recS, starts, wgmap, scratch);
  compose_k<<<(HWPIX + 255) / 256, 256, 0, stream>>>(scratch, poff, meta, (float*)d_out);
}